// Round 18
// baseline (227.249 us; speedup 1.0000x reference)
//
#include <hip/hip_runtime.h>

#define N_NODES 50000
#define E_EDGES 800000
#define HID 128
#define NQB 782   // ceil(50000/64) node-tile blocks in the fused qkvs kernel
#define SCAN_BLK 1024
#define NSB 49    // ceil(50000/1024)
#define WCB 192   // wcvt conversion blocks; blocks [WCB, WCB+49) zero deg

typedef __attribute__((ext_vector_type(8))) short short8;
typedef __attribute__((ext_vector_type(4))) float f32x4;
typedef __attribute__((ext_vector_type(2))) float f32x2;

static __device__ __forceinline__ unsigned short f2bf(float f) {
  unsigned int u = __builtin_bit_cast(unsigned int, f);
  u += 0x7fff + ((u >> 16) & 1);  // round-to-nearest-even
  return (unsigned short)(u >> 16);
}
static __device__ __forceinline__ float bf2f(unsigned short u) {
  return __builtin_bit_cast(float, (unsigned int)u << 16);
}
static __device__ __forceinline__ float bf_lo(unsigned u) {  // low bf16 -> f32
  return __builtin_bit_cast(float, u << 16);
}
static __device__ __forceinline__ float bf_hi(unsigned u) {  // high bf16 -> f32
  return __builtin_bit_cast(float, u & 0xffff0000u);
}
static __device__ __forceinline__ unsigned short pk_fp8(float a, float b) {
  return (unsigned short)(__builtin_amdgcn_cvt_pk_fp8_f32(a, b, 0, false) & 0xffff);
}

// ---- weight conversion fp32 -> bf16 + deg zeroing ---------------------------
__global__ __launch_bounds__(256) void wcvt_kernel(
    const float4* __restrict__ Wq, const float4* __restrict__ Wk,
    const float4* __restrict__ Wv, const float4* __restrict__ Ws,
    const float4* __restrict__ W1, const float4* __restrict__ W2,
    unsigned short* __restrict__ wqkvs, unsigned short* __restrict__ w1b,
    unsigned short* __restrict__ w2b, int* __restrict__ deg)
{
  if (blockIdx.x >= WCB) {  // ---- deg zero path ----
    int idx = ((blockIdx.x - WCB) * 256 + threadIdx.x) * 4;
    if (idx + 3 < N_NODES) *(int4*)(deg + idx) = (int4){0, 0, 0, 0};
    else {
      for (int t = 0; t < 4; t++)
        if (idx + t < N_NODES) deg[idx + t] = 0;
    }
    return;
  }
  int i = blockIdx.x * 256 + threadIdx.x;  // [0, 49152) float4 groups
  const float4* src;
  unsigned short* dst;
  if (i < 16384) {
    int part = i >> 12;
    src = ((part == 0) ? Wq : (part == 1) ? Wk : (part == 2) ? Wv : Ws) + (i & 4095);
    dst = wqkvs + i * 4;
  } else if (i < 32768) {
    src = W1 + (i - 16384); dst = w1b + (size_t)(i - 16384) * 4;
  } else {
    src = W2 + (i - 32768); dst = w2b + (size_t)(i - 32768) * 4;
  }
  float4 v = *src;
  ushort4 o;
  o.x = f2bf(v.x); o.y = f2bf(v.y); o.z = f2bf(v.z); o.w = f2bf(v.w);
  *(ushort4*)dst = o;
}

// ---- fused [LN1 + QKVS projection via bf16 MFMA | degree count] -------------
// kv layout: [node][32 chunks of 8B]; chunk c = {k[4c..4c+3] | v[4c..4c+3]}.
__global__ __launch_bounds__(256) void qkvs_kernel(
    const float* __restrict__ x,
    const float* __restrict__ g1, const float* __restrict__ bln,
    const unsigned short* __restrict__ wqkvs,
    const float* __restrict__ bq, const float* __restrict__ bk,
    const float* __restrict__ bv, const float* __restrict__ bs,
    unsigned short* __restrict__ qb, unsigned char* __restrict__ kvb,
    unsigned short* __restrict__ sb,
    const int* __restrict__ ei, int* __restrict__ deg, int n)
{
  if (blockIdx.x >= NQB) {  // ---- degree count path ----
    for (int e = (blockIdx.x - NQB) * 256 + threadIdx.x; e < E_EDGES;
         e += NQB * 256)
      atomicAdd(deg + ei[E_EDGES + e], 1);
    return;
  }
  __shared__ short lnA[64][128];
  int node0 = blockIdx.x * 64;
  int tid = threadIdx.x;
  int g = tid >> 4, gl = tid & 15, c0 = gl * 8;
  {
    float gv[8], bv2[8];
    *(float4*)&gv[0] = *(const float4*)(g1 + c0);
    *(float4*)&gv[4] = *(const float4*)(g1 + c0 + 4);
    *(float4*)&bv2[0] = *(const float4*)(bln + c0);
    *(float4*)&bv2[4] = *(const float4*)(bln + c0 + 4);
    for (int ni = 0; ni < 4; ni++) {
      int nl = ni * 16 + g;
      int node = node0 + nl;
      short8 h8 = {0, 0, 0, 0, 0, 0, 0, 0};
      if (node < n) {
        float vals[8];
        const float* row = x + (size_t)node * HID + c0;
        *(float4*)&vals[0] = *(const float4*)row;
        *(float4*)&vals[4] = *(const float4*)(row + 4);
        float sum = 0.f;
        #pragma unroll
        for (int j = 0; j < 8; j++) sum += vals[j];
        sum += __shfl_xor(sum, 8); sum += __shfl_xor(sum, 4);
        sum += __shfl_xor(sum, 2); sum += __shfl_xor(sum, 1);
        float mu = sum * (1.f / 128.f);
        float sq = 0.f;
        #pragma unroll
        for (int j = 0; j < 8; j++) { float d = vals[j] - mu; sq += d * d; }
        sq += __shfl_xor(sq, 8); sq += __shfl_xor(sq, 4);
        sq += __shfl_xor(sq, 2); sq += __shfl_xor(sq, 1);
        float rstd = rsqrtf(sq * (1.f / 128.f) + 1e-5f);
        #pragma unroll
        for (int j = 0; j < 8; j++)
          h8[j] = (short)f2bf((vals[j] - mu) * rstd * gv[j] + bv2[j]);
      }
      *(short8*)&lnA[nl][(gl ^ (nl & 7)) * 8] = h8;
    }
  }
  __syncthreads();
  int w = tid >> 6, lane = tid & 63;
  int lg = lane >> 4, ll = lane & 15;
  short8 bfr[4][4];
  #pragma unroll
  for (int nt = 0; nt < 4; nt++) {
    int arow = nt * 16 + ll;
    #pragma unroll
    for (int kt = 0; kt < 4; kt++)
      bfr[nt][kt] = *(const short8*)&lnA[arow][((kt * 4 + lg) ^ (ll & 7)) * 8];
  }
  const float* biasp = (w == 0) ? bq : (w == 1) ? bk : (w == 2) ? bv : bs;
  bool ok[4];
  #pragma unroll
  for (int nt = 0; nt < 4; nt++) ok[nt] = (node0 + nt * 16 + ll) < n;
  for (int ci = 0; ci < 8; ci++) {
    const unsigned short* wrow = wqkvs + (size_t)(w * 128 + ci * 16 + ll) * 128 + lg * 8;
    short8 af[4];
    #pragma unroll
    for (int kt = 0; kt < 4; kt++) af[kt] = *(const short8*)(wrow + kt * 32);
    f32x4 acc[4];
    #pragma unroll
    for (int nt = 0; nt < 4; nt++) acc[nt] = (f32x4){0.f, 0.f, 0.f, 0.f};
    #pragma unroll
    for (int kt = 0; kt < 4; kt++)
      #pragma unroll
      for (int nt = 0; nt < 4; nt++)
        acc[nt] = __builtin_amdgcn_mfma_f32_16x16x32_bf16(af[kt], bfr[nt][kt], acc[nt], 0, 0, 0);
    int jj = ci * 16 + lg * 4;  // 4 consecutive channels within this matrix
    float4 bq4 = *(const float4*)(biasp + jj);
    #pragma unroll
    for (int nt = 0; nt < 4; nt++) {
      if (!ok[nt]) continue;
      int node = node0 + nt * 16 + ll;
      float v0 = acc[nt][0] + bq4.x, v1 = acc[nt][1] + bq4.y;
      float v2 = acc[nt][2] + bq4.z, v3 = acc[nt][3] + bq4.w;
      if (w == 0 || w == 3) {
        ushort4 o;
        o.x = f2bf(v0); o.y = f2bf(v1); o.z = f2bf(v2); o.w = f2bf(v3);
        *(ushort4*)((w == 0 ? qb : sb) + (size_t)node * HID + jj) = o;
      } else {
        // chunk (jj>>2): k-word at +0, v-word at +4
        unsigned word = (unsigned)pk_fp8(v0, v1) | ((unsigned)pk_fp8(v2, v3) << 16);
        *(unsigned*)(kvb + (unsigned)node * 256 + (jj >> 2) * 8 + (w == 1 ? 0 : 4)) = word;
      }
    }
  }
}

// -------- CSR build: per-block degree sums (coalesced int4 reads) ------------
__global__ __launch_bounds__(256) void scan1_kernel(
    const int* __restrict__ deg, int* __restrict__ bsum)
{
  __shared__ int wsum[4];
  int b = blockIdx.x;
  int idx = b * SCAN_BLK + threadIdx.x * 4;
  int4 v = {0, 0, 0, 0};
  if (idx + 3 < N_NODES) v = *(const int4*)(deg + idx);
  else {
    if (idx     < N_NODES) v.x = deg[idx];
    if (idx + 1 < N_NODES) v.y = deg[idx + 1];
    if (idx + 2 < N_NODES) v.z = deg[idx + 2];
    if (idx + 3 < N_NODES) v.w = deg[idx + 3];
  }
  int s = v.x + v.y + v.z + v.w;
  for (int m = 1; m < 64; m <<= 1) s += __shfl_xor(s, m);
  int lane = threadIdx.x & 63, w = threadIdx.x >> 6;
  if (lane == 0) wsum[w] = s;
  __syncthreads();
  if (threadIdx.x == 0) bsum[b] = wsum[0] + wsum[1] + wsum[2] + wsum[3];
}

// -------- CSR build: block-local exclusive scan + global offset --------------
__global__ __launch_bounds__(256) void scan2_kernel(
    const int* __restrict__ deg, const int* __restrict__ bsum,
    int* __restrict__ row_start, int* __restrict__ cursor)
{
  __shared__ int boff_s;
  __shared__ int wsum[4];
  int b = blockIdx.x;
  int tid = threadIdx.x;
  int lane = tid & 63, w = tid >> 6;
  if (tid < 64) {  // block offset = sum of bsum[0..b)  (NSB=49 < 64)
    int v = (lane < b) ? bsum[lane] : 0;
    for (int m = 1; m < 64; m <<= 1) v += __shfl_xor(v, m);
    if (lane == 0) boff_s = v;
  }
  int idx = b * SCAN_BLK + tid * 4;
  int4 v = {0, 0, 0, 0};
  if (idx + 3 < N_NODES) v = *(const int4*)(deg + idx);
  else {
    if (idx     < N_NODES) v.x = deg[idx];
    if (idx + 1 < N_NODES) v.y = deg[idx + 1];
    if (idx + 2 < N_NODES) v.z = deg[idx + 2];
    if (idx + 3 < N_NODES) v.w = deg[idx + 3];
  }
  int ts = v.x + v.y + v.z + v.w;
  int incl = ts;
  for (int m = 1; m < 64; m <<= 1) {
    int t = __shfl_up(incl, m);
    if (lane >= m) incl += t;
  }
  if (lane == 63) wsum[w] = incl;
  __syncthreads();
  int woff = 0;
  for (int i = 0; i < w; i++) woff += wsum[i];
  int excl = boff_s + woff + incl - ts;
  int4 o;
  o.x = excl;
  o.y = excl + v.x;
  o.z = excl + v.x + v.y;
  o.w = excl + v.x + v.y + v.z;
  if (idx + 3 < N_NODES) {
    *(int4*)(row_start + idx) = o;
    *(int4*)(cursor + idx) = o;
  } else {
    if (idx     < N_NODES) { row_start[idx]     = o.x; cursor[idx]     = o.x; }
    if (idx + 1 < N_NODES) { row_start[idx + 1] = o.y; cursor[idx + 1] = o.y; }
    if (idx + 2 < N_NODES) { row_start[idx + 2] = o.z; cursor[idx + 2] = o.z; }
    if (idx + 3 < N_NODES) { row_start[idx + 3] = o.w; cursor[idx + 3] = o.w; }
  }
}

// -------- CSR build: scatter unified 16B records -----------------------------
// rec = {src_byteoff:int, attr01:2xbf16, attr23:2xbf16, pad}
__global__ __launch_bounds__(256) void scatter_kernel(
    const int* __restrict__ ei, const float4* __restrict__ attr,
    int* __restrict__ cursor, uint4* __restrict__ csr_rec)
{
  int e = blockIdx.x * 256 + threadIdx.x;
  if (e >= E_EDGES) return;
  int dst = ei[E_EDGES + e];
  float4 a4 = attr[e];
  int pos = atomicAdd(cursor + dst, 1);
  uint4 rec;
  rec.x = (unsigned)(ei[e] * 256);  // pre-multiplied byte offset into kvb
  rec.y = (unsigned)f2bf(a4.x) | ((unsigned)f2bf(a4.y) << 16);
  rec.z = (unsigned)f2bf(a4.z) | ((unsigned)f2bf(a4.w) << 16);
  rec.w = 0u;
  csr_rec[pos] = rec;
}

// -------- Gather + combine: 1 wave per dst node, 2 edge slots x 32 lanes -----
// q·(k+e) = q·k + (q^T We)·attr ;  Σ a_j e_j = We (Σ a_j attr_j).
// Lane = 4 channels (8B kv chunk); slot s = lane>>5 handles edge j+s.
// Unified 16B records scalarized via readfirstlane -> s_load_dwordx4; attr
// decoded from bf16 pairs; 2-deep SGPR record pipeline; kv on vector path.
__global__ __launch_bounds__(256) void gather_kernel(
    const int* __restrict__ row_start, const int* __restrict__ deg,
    const uint4* __restrict__ csr_rec,
    const float* __restrict__ We,
    const unsigned short* __restrict__ qb, const unsigned char* __restrict__ kvb,
    const float* __restrict__ x, const unsigned short* __restrict__ sb,
    const float* __restrict__ Wb, unsigned short* __restrict__ xnb, int n)
{
  int node = (blockIdx.x * blockDim.x + threadIdx.x) >> 6;
  if (node >= n) return;
  int nodeu = __builtin_amdgcn_readfirstlane(node);
  int lane = threadIdx.x & 63;
  int hl = lane & 31;   // half-lane: channel chunk
  int s  = lane >> 5;   // edge slot
  int c0 = hl * 4;      // 4 channels per lane
  const unsigned short* qrow = qb + (size_t)nodeu * HID;
  ushort4 q4 = *(const ushort4*)(qrow + c0);
  float q0 = bf2f(q4.x), q1 = bf2f(q4.y), q2 = bf2f(q4.z), q3 = bf2f(q4.w);
  float4 wr0 = *(const float4*)(We + (c0 + 0) * 4);
  float4 wr1 = *(const float4*)(We + (c0 + 1) * 4);
  float4 wr2 = *(const float4*)(We + (c0 + 2) * 4);
  float4 wr3 = *(const float4*)(We + (c0 + 3) * 4);
  float qwe0 = q0 * wr0.x + q1 * wr1.x + q2 * wr2.x + q3 * wr3.x;
  float qwe1 = q0 * wr0.y + q1 * wr1.y + q2 * wr2.y + q3 * wr3.y;
  float qwe2 = q0 * wr0.z + q1 * wr1.z + q2 * wr2.z + q3 * wr3.z;
  float qwe3 = q0 * wr0.w + q1 * wr1.w + q2 * wr2.w + q3 * wr3.w;
  qwe0 += __shfl_xor(qwe0, 1); qwe0 += __shfl_xor(qwe0, 2); qwe0 += __shfl_xor(qwe0, 4);
  qwe1 += __shfl_xor(qwe1, 1); qwe1 += __shfl_xor(qwe1, 2); qwe1 += __shfl_xor(qwe1, 4);
  qwe2 += __shfl_xor(qwe2, 1); qwe2 += __shfl_xor(qwe2, 2); qwe2 += __shfl_xor(qwe2, 4);
  qwe3 += __shfl_xor(qwe3, 1); qwe3 += __shfl_xor(qwe3, 2); qwe3 += __shfl_xor(qwe3, 4);
  const float s2 = 0.17677669529663687f * 1.4426950408889634f;  // /sqrt(32)*log2e
  float q0s = q0 * s2, q1s = q1 * s2, q2s = q2 * s2, q3s = q3 * s2;
  qwe0 *= s2; qwe1 *= s2; qwe2 *= s2; qwe3 *= s2;
  float acc0 = 0.f, acc1 = 0.f, acc2 = 0.f, acc3 = 0.f, den = 0.f;
  float aat0 = 0.f, aat1 = 0.f, aat2 = 0.f, aat3 = 0.f;
  int rs = row_start[nodeu];
  int cnt = deg[nodeu];
  int re = rs + cnt;
  unsigned off = (unsigned)hl * 8;
  // current records (slots rs, rs+1) in SGPRs
  int i0 = __builtin_amdgcn_readfirstlane(min(rs,     E_EDGES - 1));
  int i1 = __builtin_amdgcn_readfirstlane(min(rs + 1, E_EDGES - 1));
  uint4 rC0 = csr_rec[i0];
  uint4 rC1 = csr_rec[i1];
  unsigned srcsel = s ? rC1.x : rC0.x;
  uint2 kvc = *(const uint2*)(kvb + srcsel + off);
  float4 ac;
  ac.x = s ? bf_lo(rC1.y) : bf_lo(rC0.y);
  ac.y = s ? bf_hi(rC1.y) : bf_hi(rC0.y);
  ac.z = s ? bf_lo(rC1.z) : bf_lo(rC0.z);
  ac.w = s ? bf_hi(rC1.z) : bf_hi(rC0.z);
  // next records (slots rs+2, rs+3) in SGPRs
  int i2 = __builtin_amdgcn_readfirstlane(min(rs + 2, E_EDGES - 1));
  int i3 = __builtin_amdgcn_readfirstlane(min(rs + 3, E_EDGES - 1));
  uint4 rN0 = csr_rec[i2];
  uint4 rN1 = csr_rec[i3];
  for (int j = rs; j < re; j += 2) {
    // issue next kv load (address from SGPR-resident records)
    unsigned srcn = s ? rN1.x : rN0.x;
    uint2 kvn = *(const uint2*)(kvb + srcn + off);
    float4 an;
    an.x = s ? bf_lo(rN1.y) : bf_lo(rN0.y);
    an.y = s ? bf_hi(rN1.y) : bf_hi(rN0.y);
    an.z = s ? bf_lo(rN1.z) : bf_lo(rN0.z);
    an.w = s ? bf_hi(rN1.z) : bf_hi(rN0.z);
    // issue scalar loads for the pair after next
    int p0 = __builtin_amdgcn_readfirstlane(min(j + 4, E_EDGES - 1));
    int p1 = __builtin_amdgcn_readfirstlane(min(j + 5, E_EDGES - 1));
    uint4 rP0 = csr_rec[p0];
    uint4 rP1 = csr_rec[p1];
    // compute on current
    f32x2 k01 = __builtin_amdgcn_cvt_pk_f32_fp8((int)kvc.x, false);
    f32x2 k23 = __builtin_amdgcn_cvt_pk_f32_fp8((int)kvc.x, true);
    float dot = q0s * k01.x + q1s * k01.y + q2s * k23.x + q3s * k23.y;
    dot += __shfl_xor(dot, 1);
    dot += __shfl_xor(dot, 2);
    dot += __shfl_xor(dot, 4);
    float e = exp2f(dot + qwe0 * ac.x + qwe1 * ac.y + qwe2 * ac.z + qwe3 * ac.w);
    e = (j + s < re) ? e : 0.f;  // slot validity (max-free softmax)
    den += e;
    aat0 += e * ac.x; aat1 += e * ac.y;
    aat2 += e * ac.z; aat3 += e * ac.w;
    f32x2 v01 = __builtin_amdgcn_cvt_pk_f32_fp8((int)kvc.y, false);
    f32x2 v23 = __builtin_amdgcn_cvt_pk_f32_fp8((int)kvc.y, true);
    acc0 += e * v01.x; acc1 += e * v01.y;
    acc2 += e * v23.x; acc3 += e * v23.y;
    // rotate
    kvc = kvn; ac = an;
    rN0 = rP0; rN1 = rP1;
  }
  // ---- combine the 2 edge slots ----
  acc0 += __shfl_xor(acc0, 32); acc1 += __shfl_xor(acc1, 32);
  acc2 += __shfl_xor(acc2, 32); acc3 += __shfl_xor(acc3, 32);
  den  += __shfl_xor(den, 32);
  aat0 += __shfl_xor(aat0, 32); aat1 += __shfl_xor(aat1, 32);
  aat2 += __shfl_xor(aat2, 32); aat3 += __shfl_xor(aat3, 32);
  float inv = 1.0f / (den + 1e-16f);
  float o0 = (acc0 + wr0.x * aat0 + wr0.y * aat1 + wr0.z * aat2 + wr0.w * aat3) * inv;
  float o1 = (acc1 + wr1.x * aat0 + wr1.y * aat1 + wr1.z * aat2 + wr1.w * aat3) * inv;
  float o2 = (acc2 + wr2.x * aat0 + wr2.y * aat1 + wr2.z * aat2 + wr2.w * aat3) * inv;
  float o3 = (acc3 + wr3.x * aat0 + wr3.y * aat1 + wr3.z * aat2 + wr3.w * aat3) * inv;
  // ---- fused combine: beta gate + first residual ----
  ushort4 sp4 = *(const ushort4*)(sb + (size_t)nodeu * HID + c0);
  float sk0 = bf2f(sp4.x), sk1 = bf2f(sp4.y), sk2 = bf2f(sp4.z), sk3 = bf2f(sp4.w);
  float4 wbA = *(const float4*)(Wb + c0);
  float4 wbB = *(const float4*)(Wb + 128 + c0);
  float4 wbC = *(const float4*)(Wb + 256 + c0);
  float bpart = o0 * (wbA.x + wbC.x) + sk0 * (wbB.x - wbC.x) +
                o1 * (wbA.y + wbC.y) + sk1 * (wbB.y - wbC.y) +
                o2 * (wbA.z + wbC.z) + sk2 * (wbB.z - wbC.z) +
                o3 * (wbA.w + wbC.w) + sk3 * (wbB.w - wbC.w);
  bpart += __shfl_xor(bpart, 1); bpart += __shfl_xor(bpart, 2);
  bpart += __shfl_xor(bpart, 4); bpart += __shfl_xor(bpart, 8);
  bpart += __shfl_xor(bpart, 16);  // sum over 32 lanes (each half has full sum)
  float beta = 1.0f / (1.0f + exp2f(-bpart * 1.4426950408889634f));
  if (lane < 32) {
    float4 xv = *(const float4*)(x + (size_t)nodeu * HID + c0);
    ushort4 o4;
    o4.x = f2bf(xv.x + beta * sk0 + (1.0f - beta) * o0);
    o4.y = f2bf(xv.y + beta * sk1 + (1.0f - beta) * o1);
    o4.z = f2bf(xv.z + beta * sk2 + (1.0f - beta) * o2);
    o4.w = f2bf(xv.w + beta * sk3 + (1.0f - beta) * o3);
    *(ushort4*)(xnb + (size_t)nodeu * HID + c0) = o4;
  }
}

// ---- fused LN2 + MLP (GEMM1 relu GEMM2) via bf16 MFMA + residual ------------
// 512 threads (8 waves), 32-node tile, 40KB LDS -> 4 blocks x 8 waves = 32
// waves/CU occupancy cap. GEMM1: wave w owns j-tiles [w*4,w*4+4); GEMM2:
// wave w owns c-tile w.
__global__ __launch_bounds__(512) void mlp_kernel(
    const unsigned short* __restrict__ xnb,
    const float* __restrict__ g2, const float* __restrict__ b2ln,
    const unsigned short* __restrict__ w1b, const float* __restrict__ b1,
    const unsigned short* __restrict__ w2b, const float* __restrict__ b2,
    float* __restrict__ out, int n)
{
  __shared__ short lnA[32][128];
  __shared__ short tS[32][512];
  short* tsf = &tS[0][0];
  int node0 = blockIdx.x * 32;
  int tid = threadIdx.x;
  int g = tid >> 4, gl = tid & 15, c0 = gl * 8;
  {
    // 512 threads: 32 rows x 16 threads, single pass
    float gv[8], bv2[8];
    *(float4*)&gv[0] = *(const float4*)(g2 + c0);
    *(float4*)&gv[4] = *(const float4*)(g2 + c0 + 4);
    *(float4*)&bv2[0] = *(const float4*)(b2ln + c0);
    *(float4*)&bv2[4] = *(const float4*)(b2ln + c0 + 4);
    int nl = g;
    int node = node0 + nl;
    short8 h8 = {0, 0, 0, 0, 0, 0, 0, 0};
    if (node < n) {
      short8 raw = *(const short8*)(xnb + (size_t)node * HID + c0);
      float vals[8];
      #pragma unroll
      for (int j = 0; j < 8; j++) vals[j] = bf2f((unsigned short)raw[j]);
      float sum = 0.f;
      #pragma unroll
      for (int j = 0; j < 8; j++) sum += vals[j];
      sum += __shfl_xor(sum, 8); sum += __shfl_xor(sum, 4);
      sum += __shfl_xor(sum, 2); sum += __shfl_xor(sum, 1);
      float mu = sum * (1.f / 128.f);
      float sq = 0.f;
      #pragma unroll
      for (int j = 0; j < 8; j++) { float d = vals[j] - mu; sq += d * d; }
      sq += __shfl_xor(sq, 8); sq += __shfl_xor(sq, 4);
      sq += __shfl_xor(sq, 2); sq += __shfl_xor(sq, 1);
      float rstd = rsqrtf(sq * (1.f / 128.f) + 1e-5f);
      #pragma unroll
      for (int j = 0; j < 8; j++)
        h8[j] = (short)f2bf((vals[j] - mu) * rstd * gv[j] + bv2[j]);
    }
    *(short8*)&lnA[nl][(gl ^ (nl & 7)) * 8] = h8;
  }
  __syncthreads();
  int w = tid >> 6, lane = tid & 63;
  int lg = lane >> 4, ll = lane & 15;
  int swz = (ll & 7) << 1;  // tS granule XOR (node = nt*16+ll -> node&7 = ll&7)
  bool ok0 = (node0 + ll) < n, ok1 = (node0 + 16 + ll) < n;
  // ---- GEMM1: D[j][node]; wave w owns j-tiles [w*4, w*4+4), both node-tiles
  {
    short8 bfr1[2][4];
    #pragma unroll
    for (int nt = 0; nt < 2; nt++) {
      int arow = nt * 16 + ll;
      #pragma unroll
      for (int kt = 0; kt < 4; kt++)
        bfr1[nt][kt] = *(const short8*)&lnA[arow][((kt * 4 + lg) ^ (ll & 7)) * 8];
    }
    for (int ji = 0; ji < 4; ji++) {
      int jt = w * 4 + ji;
      const unsigned short* wrow = w1b + (size_t)(jt * 16 + ll) * 128 + lg * 8;
      short8 af[4];
      #pragma unroll
      for (int kt = 0; kt < 4; kt++) af[kt] = *(const short8*)(wrow + kt * 32);
      f32x4 acc[2];
      acc[0] = (f32x4){0.f, 0.f, 0.f, 0.f};
      acc[1] = (f32x4){0.f, 0.f, 0.f, 0.f};
      #pragma unroll
      for (int kt = 0; kt < 4; kt++) {
        acc[0] = __builtin_amdgcn_mfma_f32_16x16x32_bf16(af[kt], bfr1[0][kt], acc[0], 0, 0, 0);
        acc[1] = __builtin_amdgcn_mfma_f32_16x16x32_bf16(af[kt], bfr1[1][kt], acc[1], 0, 0, 0);
      }
      float4 bj = *(const float4*)(b1 + jt * 16 + lg * 4);
      int gr = jt * 4 + lg;  // logical 8B granule (4 consecutive j)
      #pragma unroll
      for (int nt = 0; nt < 2; nt++) {
        int nl = nt * 16 + ll;
        ushort4 o;
        o.x = f2bf(fmaxf(acc[nt][0] + bj.x, 0.f));
        o.y = f2bf(fmaxf(acc[nt][1] + bj.y, 0.f));
        o.z = f2bf(fmaxf(acc[nt][2] + bj.z, 0.f));
        o.w = f2bf(fmaxf(acc[nt][3] + bj.w, 0.f));
        *(ushort4*)&tsf[nl * 512 + (gr ^ swz) * 4] = o;
      }
    }
  }
  __syncthreads();
  // ---- GEMM2: D[c][node]; wave w owns c-tile w, both node-tiles ------------
  {
    int ct = w;
    f32x4 acc[2];
    acc[0] = (f32x4){0.f, 0.f, 0.f, 0.f};
    acc[1] = (f32x4){0.f, 0.f, 0.f, 0.f};
    const unsigned short* wrow = w2b + (size_t)(ct * 16 + ll) * 512 + lg * 8;
    #pragma unroll
    for (int kt = 0; kt < 16; kt++) {
      short8 af = *(const short8*)(wrow + kt * 32);
      int G = kt * 8 + lg * 2;  // logical granule pair base (even)
      short8 b0 = *(const short8*)&tsf[(0 * 16 + ll) * 512 + (G ^ swz) * 4];
      short8 b1f = *(const short8*)&tsf[(1 * 16 + ll) * 512 + (G ^ swz) * 4];
      acc[0] = __builtin_amdgcn_mfma_f32_16x16x32_bf16(af, b0, acc[0], 0, 0, 0);
      acc[1] = __builtin_amdgcn_mfma_f32_16x16x32_bf16(af, b1f, acc[1], 0, 0, 0);
    }
    int c = ct * 16 + lg * 4;
    float4 b2q = *(const float4*)(b2 + c);
    #pragma unroll
    for (int nt = 0; nt < 2; nt++) {
      if (nt == 0 ? !ok0 : !ok1) continue;
      int node = node0 + nt * 16 + ll;
      ushort4 xr = *(const ushort4*)(xnb + (size_t)node * HID + c);
      float4 o;
      o.x = bf2f(xr.x) + acc[nt][0] + b2q.x;
      o.y = bf2f(xr.y) + acc[nt][1] + b2q.y;
      o.z = bf2f(xr.z) + acc[nt][2] + b2q.z;
      o.w = bf2f(xr.w) + acc[nt][3] + b2q.w;
      *(float4*)(out + (size_t)node * HID + c) = o;
    }
  }
}

extern "C" void kernel_launch(void* const* d_in, const int* in_sizes, int n_in,
                              void* d_out, int out_size, void* d_ws, size_t ws_size,
                              hipStream_t stream) {
  const float* x     = (const float*)d_in[0];
  const int*   ei    = (const int*)d_in[1];
  const float* attr  = (const float*)d_in[2];
  const float* ln1_g = (const float*)d_in[3];
  const float* ln1_b = (const float*)d_in[4];
  const float* Wq    = (const float*)d_in[5];
  const float* bq    = (const float*)d_in[6];
  const float* Wk    = (const float*)d_in[7];
  const float* bk    = (const float*)d_in[8];
  const float* Wv    = (const float*)d_in[9];
  const float* bv    = (const float*)d_in[10];
  const float* We    = (const float*)d_in[11];
  const float* Wskip = (const float*)d_in[12];
  const float* bskip = (const float*)d_in[13];
  const float* Wbeta = (const float*)d_in[14];
  const float* ln2_g = (const float*)d_in[15];
  const float* ln2_b = (const float*)d_in[16];
  const float* W1    = (const float*)d_in[17];
  const float* b1    = (const float*)d_in[18];
  const float* W2    = (const float*)d_in[19];
  const float* b2    = (const float*)d_in[20];
  float* out = (float*)d_out;
  float* ws  = (float*)d_ws;

  size_t NH  = (size_t)N_NODES * HID;  // 6.4M elements
  size_t NHf = NH / 2;                 // ushort array size in float units
  unsigned short* sb  = (unsigned short*)ws;             // [N][128] bf16 skip
  unsigned short* xnb = (unsigned short*)(ws + NHf);     // [N][128] bf16 xn
  unsigned short* qb  = (unsigned short*)(ws + 2 * NHf); // [N][128] bf16 q
  unsigned char*  kvb = (unsigned char*)(ws + 3 * NHf);  // [N][256] fp8 chunks
  float* base2 = ws + 3 * NHf + (size_t)N_NODES * 256 / 4;
  int* deg       = (int*)base2;
  int* row_start = deg + N_NODES;
  int* cursor    = row_start + N_NODES;
  // 3*N ints = 150000; pad to 16B boundary (150000 % 4 == 0) -> csr_rec aligned
  uint4* csr_rec = (uint4*)(base2 + 150000);
  unsigned short* wqkvs = (unsigned short*)(base2 + 150000 + (size_t)E_EDGES * 4);
  unsigned short* w1b   = wqkvs + 65536;
  unsigned short* w2b   = w1b + 65536;
  int* bsum = (int*)(w2b + 65536);  // NSB=49 block sums

  wcvt_kernel<<<WCB + NSB, 256, 0, stream>>>(
      (const float4*)Wq, (const float4*)Wk, (const float4*)Wv,
      (const float4*)Wskip, (const float4*)W1, (const float4*)W2,
      wqkvs, w1b, w2b, deg);
  qkvs_kernel<<<2 * NQB, 256, 0, stream>>>(
      x, ln1_g, ln1_b, wqkvs, bq, bk, bv, bskip, qb, kvb, sb, ei, deg, N_NODES);
  scan1_kernel<<<NSB, 256, 0, stream>>>(deg, bsum);
  scan2_kernel<<<NSB, 256, 0, stream>>>(deg, bsum, row_start, cursor);
  scatter_kernel<<<(E_EDGES + 255) / 256, 256, 0, stream>>>(
      ei, (const float4*)attr, cursor, csr_rec);
  gather_kernel<<<(N_NODES * 64 + 255) / 256, 256, 0, stream>>>(
      row_start, deg, csr_rec, We, qb, kvb, x, sb, Wbeta, xnb, N_NODES);
  mlp_kernel<<<(N_NODES + 31) / 32, 512, 0, stream>>>(
      xnb, ln2_g, ln2_b, w1b, b1, w2b, b2, out, N_NODES);
}

// Round 19
// 226.714 us; speedup vs baseline: 1.0024x; 1.0024x over previous
//
#include <hip/hip_runtime.h>

#define N_NODES 50000
#define E_EDGES 800000
#define HID 128
#define NQB 782   // ceil(50000/64) node-tile blocks in the fused qkvs kernel
#define SCAN_BLK 1024
#define NSB 49    // ceil(50000/1024)
#define WCB 192   // wcvt conversion blocks; blocks [WCB, WCB+49) zero deg

typedef __attribute__((ext_vector_type(8))) short short8;
typedef __attribute__((ext_vector_type(4))) float f32x4;
typedef __attribute__((ext_vector_type(2))) float f32x2;

static __device__ __forceinline__ unsigned short f2bf(float f) {
  unsigned int u = __builtin_bit_cast(unsigned int, f);
  u += 0x7fff + ((u >> 16) & 1);  // round-to-nearest-even
  return (unsigned short)(u >> 16);
}
static __device__ __forceinline__ float bf2f(unsigned short u) {
  return __builtin_bit_cast(float, (unsigned int)u << 16);
}
static __device__ __forceinline__ float bf_lo(unsigned u) {  // low bf16 -> f32
  return __builtin_bit_cast(float, u << 16);
}
static __device__ __forceinline__ float bf_hi(unsigned u) {  // high bf16 -> f32
  return __builtin_bit_cast(float, u & 0xffff0000u);
}
static __device__ __forceinline__ unsigned short pk_fp8(float a, float b) {
  return (unsigned short)(__builtin_amdgcn_cvt_pk_fp8_f32(a, b, 0, false) & 0xffff);
}

// ---- weight conversion fp32 -> bf16 + deg zeroing ---------------------------
__global__ __launch_bounds__(256) void wcvt_kernel(
    const float4* __restrict__ Wq, const float4* __restrict__ Wk,
    const float4* __restrict__ Wv, const float4* __restrict__ Ws,
    const float4* __restrict__ W1, const float4* __restrict__ W2,
    unsigned short* __restrict__ wqkvs, unsigned short* __restrict__ w1b,
    unsigned short* __restrict__ w2b, int* __restrict__ deg)
{
  if (blockIdx.x >= WCB) {  // ---- deg zero path ----
    int idx = ((blockIdx.x - WCB) * 256 + threadIdx.x) * 4;
    if (idx + 3 < N_NODES) *(int4*)(deg + idx) = (int4){0, 0, 0, 0};
    else {
      for (int t = 0; t < 4; t++)
        if (idx + t < N_NODES) deg[idx + t] = 0;
    }
    return;
  }
  int i = blockIdx.x * 256 + threadIdx.x;  // [0, 49152) float4 groups
  const float4* src;
  unsigned short* dst;
  if (i < 16384) {
    int part = i >> 12;
    src = ((part == 0) ? Wq : (part == 1) ? Wk : (part == 2) ? Wv : Ws) + (i & 4095);
    dst = wqkvs + i * 4;
  } else if (i < 32768) {
    src = W1 + (i - 16384); dst = w1b + (size_t)(i - 16384) * 4;
  } else {
    src = W2 + (i - 32768); dst = w2b + (size_t)(i - 32768) * 4;
  }
  float4 v = *src;
  ushort4 o;
  o.x = f2bf(v.x); o.y = f2bf(v.y); o.z = f2bf(v.z); o.w = f2bf(v.w);
  *(ushort4*)dst = o;
}

// ---- fused [LN1 + QKVS projection via bf16 MFMA | degree count] -------------
// kv layout: [node][32 chunks of 8B]; chunk c = {k[4c..4c+3] | v[4c..4c+3]}.
__global__ __launch_bounds__(256) void qkvs_kernel(
    const float* __restrict__ x,
    const float* __restrict__ g1, const float* __restrict__ bln,
    const unsigned short* __restrict__ wqkvs,
    const float* __restrict__ bq, const float* __restrict__ bk,
    const float* __restrict__ bv, const float* __restrict__ bs,
    unsigned short* __restrict__ qb, unsigned char* __restrict__ kvb,
    unsigned short* __restrict__ sb,
    const int* __restrict__ ei, int* __restrict__ deg, int n)
{
  if (blockIdx.x >= NQB) {  // ---- degree count path ----
    for (int e = (blockIdx.x - NQB) * 256 + threadIdx.x; e < E_EDGES;
         e += NQB * 256)
      atomicAdd(deg + ei[E_EDGES + e], 1);
    return;
  }
  __shared__ short lnA[64][128];
  int node0 = blockIdx.x * 64;
  int tid = threadIdx.x;
  int g = tid >> 4, gl = tid & 15, c0 = gl * 8;
  {
    float gv[8], bv2[8];
    *(float4*)&gv[0] = *(const float4*)(g1 + c0);
    *(float4*)&gv[4] = *(const float4*)(g1 + c0 + 4);
    *(float4*)&bv2[0] = *(const float4*)(bln + c0);
    *(float4*)&bv2[4] = *(const float4*)(bln + c0 + 4);
    for (int ni = 0; ni < 4; ni++) {
      int nl = ni * 16 + g;
      int node = node0 + nl;
      short8 h8 = {0, 0, 0, 0, 0, 0, 0, 0};
      if (node < n) {
        float vals[8];
        const float* row = x + (size_t)node * HID + c0;
        *(float4*)&vals[0] = *(const float4*)row;
        *(float4*)&vals[4] = *(const float4*)(row + 4);
        float sum = 0.f;
        #pragma unroll
        for (int j = 0; j < 8; j++) sum += vals[j];
        sum += __shfl_xor(sum, 8); sum += __shfl_xor(sum, 4);
        sum += __shfl_xor(sum, 2); sum += __shfl_xor(sum, 1);
        float mu = sum * (1.f / 128.f);
        float sq = 0.f;
        #pragma unroll
        for (int j = 0; j < 8; j++) { float d = vals[j] - mu; sq += d * d; }
        sq += __shfl_xor(sq, 8); sq += __shfl_xor(sq, 4);
        sq += __shfl_xor(sq, 2); sq += __shfl_xor(sq, 1);
        float rstd = rsqrtf(sq * (1.f / 128.f) + 1e-5f);
        #pragma unroll
        for (int j = 0; j < 8; j++)
          h8[j] = (short)f2bf((vals[j] - mu) * rstd * gv[j] + bv2[j]);
      }
      *(short8*)&lnA[nl][(gl ^ (nl & 7)) * 8] = h8;
    }
  }
  __syncthreads();
  int w = tid >> 6, lane = tid & 63;
  int lg = lane >> 4, ll = lane & 15;
  short8 bfr[4][4];
  #pragma unroll
  for (int nt = 0; nt < 4; nt++) {
    int arow = nt * 16 + ll;
    #pragma unroll
    for (int kt = 0; kt < 4; kt++)
      bfr[nt][kt] = *(const short8*)&lnA[arow][((kt * 4 + lg) ^ (ll & 7)) * 8];
  }
  const float* biasp = (w == 0) ? bq : (w == 1) ? bk : (w == 2) ? bv : bs;
  bool ok[4];
  #pragma unroll
  for (int nt = 0; nt < 4; nt++) ok[nt] = (node0 + nt * 16 + ll) < n;
  for (int ci = 0; ci < 8; ci++) {
    const unsigned short* wrow = wqkvs + (size_t)(w * 128 + ci * 16 + ll) * 128 + lg * 8;
    short8 af[4];
    #pragma unroll
    for (int kt = 0; kt < 4; kt++) af[kt] = *(const short8*)(wrow + kt * 32);
    f32x4 acc[4];
    #pragma unroll
    for (int nt = 0; nt < 4; nt++) acc[nt] = (f32x4){0.f, 0.f, 0.f, 0.f};
    #pragma unroll
    for (int kt = 0; kt < 4; kt++)
      #pragma unroll
      for (int nt = 0; nt < 4; nt++)
        acc[nt] = __builtin_amdgcn_mfma_f32_16x16x32_bf16(af[kt], bfr[nt][kt], acc[nt], 0, 0, 0);
    int jj = ci * 16 + lg * 4;  // 4 consecutive channels within this matrix
    float4 bq4 = *(const float4*)(biasp + jj);
    #pragma unroll
    for (int nt = 0; nt < 4; nt++) {
      if (!ok[nt]) continue;
      int node = node0 + nt * 16 + ll;
      float v0 = acc[nt][0] + bq4.x, v1 = acc[nt][1] + bq4.y;
      float v2 = acc[nt][2] + bq4.z, v3 = acc[nt][3] + bq4.w;
      if (w == 0 || w == 3) {
        ushort4 o;
        o.x = f2bf(v0); o.y = f2bf(v1); o.z = f2bf(v2); o.w = f2bf(v3);
        *(ushort4*)((w == 0 ? qb : sb) + (size_t)node * HID + jj) = o;
      } else {
        // chunk (jj>>2): k-word at +0, v-word at +4
        unsigned word = (unsigned)pk_fp8(v0, v1) | ((unsigned)pk_fp8(v2, v3) << 16);
        *(unsigned*)(kvb + (unsigned)node * 256 + (jj >> 2) * 8 + (w == 1 ? 0 : 4)) = word;
      }
    }
  }
}

// -------- CSR build: per-block degree sums (coalesced int4 reads) ------------
__global__ __launch_bounds__(256) void scan1_kernel(
    const int* __restrict__ deg, int* __restrict__ bsum)
{
  __shared__ int wsum[4];
  int b = blockIdx.x;
  int idx = b * SCAN_BLK + threadIdx.x * 4;
  int4 v = {0, 0, 0, 0};
  if (idx + 3 < N_NODES) v = *(const int4*)(deg + idx);
  else {
    if (idx     < N_NODES) v.x = deg[idx];
    if (idx + 1 < N_NODES) v.y = deg[idx + 1];
    if (idx + 2 < N_NODES) v.z = deg[idx + 2];
    if (idx + 3 < N_NODES) v.w = deg[idx + 3];
  }
  int s = v.x + v.y + v.z + v.w;
  for (int m = 1; m < 64; m <<= 1) s += __shfl_xor(s, m);
  int lane = threadIdx.x & 63, w = threadIdx.x >> 6;
  if (lane == 0) wsum[w] = s;
  __syncthreads();
  if (threadIdx.x == 0) bsum[b] = wsum[0] + wsum[1] + wsum[2] + wsum[3];
}

// -------- CSR build: block-local exclusive scan + global offset --------------
__global__ __launch_bounds__(256) void scan2_kernel(
    const int* __restrict__ deg, const int* __restrict__ bsum,
    int* __restrict__ row_start, int* __restrict__ cursor)
{
  __shared__ int boff_s;
  __shared__ int wsum[4];
  int b = blockIdx.x;
  int tid = threadIdx.x;
  int lane = tid & 63, w = tid >> 6;
  if (tid < 64) {  // block offset = sum of bsum[0..b)  (NSB=49 < 64)
    int v = (lane < b) ? bsum[lane] : 0;
    for (int m = 1; m < 64; m <<= 1) v += __shfl_xor(v, m);
    if (lane == 0) boff_s = v;
  }
  int idx = b * SCAN_BLK + tid * 4;
  int4 v = {0, 0, 0, 0};
  if (idx + 3 < N_NODES) v = *(const int4*)(deg + idx);
  else {
    if (idx     < N_NODES) v.x = deg[idx];
    if (idx + 1 < N_NODES) v.y = deg[idx + 1];
    if (idx + 2 < N_NODES) v.z = deg[idx + 2];
    if (idx + 3 < N_NODES) v.w = deg[idx + 3];
  }
  int ts = v.x + v.y + v.z + v.w;
  int incl = ts;
  for (int m = 1; m < 64; m <<= 1) {
    int t = __shfl_up(incl, m);
    if (lane >= m) incl += t;
  }
  if (lane == 63) wsum[w] = incl;
  __syncthreads();
  int woff = 0;
  for (int i = 0; i < w; i++) woff += wsum[i];
  int excl = boff_s + woff + incl - ts;
  int4 o;
  o.x = excl;
  o.y = excl + v.x;
  o.z = excl + v.x + v.y;
  o.w = excl + v.x + v.y + v.z;
  if (idx + 3 < N_NODES) {
    *(int4*)(row_start + idx) = o;
    *(int4*)(cursor + idx) = o;
  } else {
    if (idx     < N_NODES) { row_start[idx]     = o.x; cursor[idx]     = o.x; }
    if (idx + 1 < N_NODES) { row_start[idx + 1] = o.y; cursor[idx + 1] = o.y; }
    if (idx + 2 < N_NODES) { row_start[idx + 2] = o.z; cursor[idx + 2] = o.z; }
    if (idx + 3 < N_NODES) { row_start[idx + 3] = o.w; cursor[idx + 3] = o.w; }
  }
}

// -------- CSR build: scatter unified 16B records -----------------------------
// rec = {src_byteoff:int, attr01:2xbf16, attr23:2xbf16, pad}
__global__ __launch_bounds__(256) void scatter_kernel(
    const int* __restrict__ ei, const float4* __restrict__ attr,
    int* __restrict__ cursor, uint4* __restrict__ csr_rec)
{
  int e = blockIdx.x * 256 + threadIdx.x;
  if (e >= E_EDGES) return;
  int dst = ei[E_EDGES + e];
  float4 a4 = attr[e];
  int pos = atomicAdd(cursor + dst, 1);
  uint4 rec;
  rec.x = (unsigned)(ei[e] * 256);  // pre-multiplied byte offset into kvb
  rec.y = (unsigned)f2bf(a4.x) | ((unsigned)f2bf(a4.y) << 16);
  rec.z = (unsigned)f2bf(a4.z) | ((unsigned)f2bf(a4.w) << 16);
  rec.w = 0u;
  csr_rec[pos] = rec;
}

// -------- Gather + combine: 1 wave per dst node, 2 edge slots x 32 lanes -----
// q·(k+e) = q·k + (q^T We)·attr ;  Σ a_j e_j = We (Σ a_j attr_j).
// Lane = 4 channels (8B kv chunk); slot s = lane>>5 handles edge j+s.
// Unified 16B records scalarized via readfirstlane -> s_load_dwordx4; attr
// decoded from bf16 pairs; 2-deep SGPR record pipeline; kv on vector path.
__global__ __launch_bounds__(256) void gather_kernel(
    const int* __restrict__ row_start, const int* __restrict__ deg,
    const uint4* __restrict__ csr_rec,
    const float* __restrict__ We,
    const unsigned short* __restrict__ qb, const unsigned char* __restrict__ kvb,
    const float* __restrict__ x, const unsigned short* __restrict__ sb,
    const float* __restrict__ Wb, unsigned short* __restrict__ xnb, int n)
{
  int node = (blockIdx.x * blockDim.x + threadIdx.x) >> 6;
  if (node >= n) return;
  int nodeu = __builtin_amdgcn_readfirstlane(node);
  int lane = threadIdx.x & 63;
  int hl = lane & 31;   // half-lane: channel chunk
  int s  = lane >> 5;   // edge slot
  int c0 = hl * 4;      // 4 channels per lane
  const unsigned short* qrow = qb + (size_t)nodeu * HID;
  ushort4 q4 = *(const ushort4*)(qrow + c0);
  float q0 = bf2f(q4.x), q1 = bf2f(q4.y), q2 = bf2f(q4.z), q3 = bf2f(q4.w);
  float4 wr0 = *(const float4*)(We + (c0 + 0) * 4);
  float4 wr1 = *(const float4*)(We + (c0 + 1) * 4);
  float4 wr2 = *(const float4*)(We + (c0 + 2) * 4);
  float4 wr3 = *(const float4*)(We + (c0 + 3) * 4);
  float qwe0 = q0 * wr0.x + q1 * wr1.x + q2 * wr2.x + q3 * wr3.x;
  float qwe1 = q0 * wr0.y + q1 * wr1.y + q2 * wr2.y + q3 * wr3.y;
  float qwe2 = q0 * wr0.z + q1 * wr1.z + q2 * wr2.z + q3 * wr3.z;
  float qwe3 = q0 * wr0.w + q1 * wr1.w + q2 * wr2.w + q3 * wr3.w;
  qwe0 += __shfl_xor(qwe0, 1); qwe0 += __shfl_xor(qwe0, 2); qwe0 += __shfl_xor(qwe0, 4);
  qwe1 += __shfl_xor(qwe1, 1); qwe1 += __shfl_xor(qwe1, 2); qwe1 += __shfl_xor(qwe1, 4);
  qwe2 += __shfl_xor(qwe2, 1); qwe2 += __shfl_xor(qwe2, 2); qwe2 += __shfl_xor(qwe2, 4);
  qwe3 += __shfl_xor(qwe3, 1); qwe3 += __shfl_xor(qwe3, 2); qwe3 += __shfl_xor(qwe3, 4);
  const float s2 = 0.17677669529663687f * 1.4426950408889634f;  // /sqrt(32)*log2e
  float q0s = q0 * s2, q1s = q1 * s2, q2s = q2 * s2, q3s = q3 * s2;
  qwe0 *= s2; qwe1 *= s2; qwe2 *= s2; qwe3 *= s2;
  float acc0 = 0.f, acc1 = 0.f, acc2 = 0.f, acc3 = 0.f, den = 0.f;
  float aat0 = 0.f, aat1 = 0.f, aat2 = 0.f, aat3 = 0.f;
  int rs = row_start[nodeu];
  int cnt = deg[nodeu];
  int re = rs + cnt;
  unsigned off = (unsigned)hl * 8;
  // current records (slots rs, rs+1) in SGPRs
  int i0 = __builtin_amdgcn_readfirstlane(min(rs,     E_EDGES - 1));
  int i1 = __builtin_amdgcn_readfirstlane(min(rs + 1, E_EDGES - 1));
  uint4 rC0 = csr_rec[i0];
  uint4 rC1 = csr_rec[i1];
  unsigned srcsel = s ? rC1.x : rC0.x;
  uint2 kvc = *(const uint2*)(kvb + srcsel + off);
  float4 ac;
  ac.x = s ? bf_lo(rC1.y) : bf_lo(rC0.y);
  ac.y = s ? bf_hi(rC1.y) : bf_hi(rC0.y);
  ac.z = s ? bf_lo(rC1.z) : bf_lo(rC0.z);
  ac.w = s ? bf_hi(rC1.z) : bf_hi(rC0.z);
  // next records (slots rs+2, rs+3) in SGPRs
  int i2 = __builtin_amdgcn_readfirstlane(min(rs + 2, E_EDGES - 1));
  int i3 = __builtin_amdgcn_readfirstlane(min(rs + 3, E_EDGES - 1));
  uint4 rN0 = csr_rec[i2];
  uint4 rN1 = csr_rec[i3];
  for (int j = rs; j < re; j += 2) {
    // issue next kv load (address from SGPR-resident records)
    unsigned srcn = s ? rN1.x : rN0.x;
    uint2 kvn = *(const uint2*)(kvb + srcn + off);
    float4 an;
    an.x = s ? bf_lo(rN1.y) : bf_lo(rN0.y);
    an.y = s ? bf_hi(rN1.y) : bf_hi(rN0.y);
    an.z = s ? bf_lo(rN1.z) : bf_lo(rN0.z);
    an.w = s ? bf_hi(rN1.z) : bf_hi(rN0.z);
    // issue scalar loads for the pair after next
    int p0 = __builtin_amdgcn_readfirstlane(min(j + 4, E_EDGES - 1));
    int p1 = __builtin_amdgcn_readfirstlane(min(j + 5, E_EDGES - 1));
    uint4 rP0 = csr_rec[p0];
    uint4 rP1 = csr_rec[p1];
    // compute on current
    f32x2 k01 = __builtin_amdgcn_cvt_pk_f32_fp8((int)kvc.x, false);
    f32x2 k23 = __builtin_amdgcn_cvt_pk_f32_fp8((int)kvc.x, true);
    float dot = q0s * k01.x + q1s * k01.y + q2s * k23.x + q3s * k23.y;
    dot += __shfl_xor(dot, 1);
    dot += __shfl_xor(dot, 2);
    dot += __shfl_xor(dot, 4);
    float e = exp2f(dot + qwe0 * ac.x + qwe1 * ac.y + qwe2 * ac.z + qwe3 * ac.w);
    e = (j + s < re) ? e : 0.f;  // slot validity (max-free softmax)
    den += e;
    aat0 += e * ac.x; aat1 += e * ac.y;
    aat2 += e * ac.z; aat3 += e * ac.w;
    f32x2 v01 = __builtin_amdgcn_cvt_pk_f32_fp8((int)kvc.y, false);
    f32x2 v23 = __builtin_amdgcn_cvt_pk_f32_fp8((int)kvc.y, true);
    acc0 += e * v01.x; acc1 += e * v01.y;
    acc2 += e * v23.x; acc3 += e * v23.y;
    // rotate
    kvc = kvn; ac = an;
    rN0 = rP0; rN1 = rP1;
  }
  // ---- combine the 2 edge slots ----
  acc0 += __shfl_xor(acc0, 32); acc1 += __shfl_xor(acc1, 32);
  acc2 += __shfl_xor(acc2, 32); acc3 += __shfl_xor(acc3, 32);
  den  += __shfl_xor(den, 32);
  aat0 += __shfl_xor(aat0, 32); aat1 += __shfl_xor(aat1, 32);
  aat2 += __shfl_xor(aat2, 32); aat3 += __shfl_xor(aat3, 32);
  float inv = 1.0f / (den + 1e-16f);
  float o0 = (acc0 + wr0.x * aat0 + wr0.y * aat1 + wr0.z * aat2 + wr0.w * aat3) * inv;
  float o1 = (acc1 + wr1.x * aat0 + wr1.y * aat1 + wr1.z * aat2 + wr1.w * aat3) * inv;
  float o2 = (acc2 + wr2.x * aat0 + wr2.y * aat1 + wr2.z * aat2 + wr2.w * aat3) * inv;
  float o3 = (acc3 + wr3.x * aat0 + wr3.y * aat1 + wr3.z * aat2 + wr3.w * aat3) * inv;
  // ---- fused combine: beta gate + first residual ----
  ushort4 sp4 = *(const ushort4*)(sb + (size_t)nodeu * HID + c0);
  float sk0 = bf2f(sp4.x), sk1 = bf2f(sp4.y), sk2 = bf2f(sp4.z), sk3 = bf2f(sp4.w);
  float4 wbA = *(const float4*)(Wb + c0);
  float4 wbB = *(const float4*)(Wb + 128 + c0);
  float4 wbC = *(const float4*)(Wb + 256 + c0);
  float bpart = o0 * (wbA.x + wbC.x) + sk0 * (wbB.x - wbC.x) +
                o1 * (wbA.y + wbC.y) + sk1 * (wbB.y - wbC.y) +
                o2 * (wbA.z + wbC.z) + sk2 * (wbB.z - wbC.z) +
                o3 * (wbA.w + wbC.w) + sk3 * (wbB.w - wbC.w);
  bpart += __shfl_xor(bpart, 1); bpart += __shfl_xor(bpart, 2);
  bpart += __shfl_xor(bpart, 4); bpart += __shfl_xor(bpart, 8);
  bpart += __shfl_xor(bpart, 16);  // sum over 32 lanes (each half has full sum)
  float beta = 1.0f / (1.0f + exp2f(-bpart * 1.4426950408889634f));
  if (lane < 32) {
    float4 xv = *(const float4*)(x + (size_t)nodeu * HID + c0);
    ushort4 o4;
    o4.x = f2bf(xv.x + beta * sk0 + (1.0f - beta) * o0);
    o4.y = f2bf(xv.y + beta * sk1 + (1.0f - beta) * o1);
    o4.z = f2bf(xv.z + beta * sk2 + (1.0f - beta) * o2);
    o4.w = f2bf(xv.w + beta * sk3 + (1.0f - beta) * o3);
    *(ushort4*)(xnb + (size_t)nodeu * HID + c0) = o4;
  }
}

// ---- fused LN2 + MLP (GEMM1 relu GEMM2) via bf16 MFMA + residual ------------
// 512 threads (8 waves), 32-node tile, 40KB LDS. Weight loads batched into
// explicit fragment arrays (8 frags per window) so L2 latency is paid in 2
// windows per GEMM instead of per-iteration serialized waits.
__global__ __launch_bounds__(512) void mlp_kernel(
    const unsigned short* __restrict__ xnb,
    const float* __restrict__ g2, const float* __restrict__ b2ln,
    const unsigned short* __restrict__ w1b, const float* __restrict__ b1,
    const unsigned short* __restrict__ w2b, const float* __restrict__ b2,
    float* __restrict__ out, int n)
{
  __shared__ short lnA[32][128];
  __shared__ short tS[32][512];
  short* tsf = &tS[0][0];
  int node0 = blockIdx.x * 32;
  int tid = threadIdx.x;
  int g = tid >> 4, gl = tid & 15, c0 = gl * 8;
  {
    // 512 threads: 32 rows x 16 threads, single pass
    float gv[8], bv2[8];
    *(float4*)&gv[0] = *(const float4*)(g2 + c0);
    *(float4*)&gv[4] = *(const float4*)(g2 + c0 + 4);
    *(float4*)&bv2[0] = *(const float4*)(b2ln + c0);
    *(float4*)&bv2[4] = *(const float4*)(b2ln + c0 + 4);
    int nl = g;
    int node = node0 + nl;
    short8 h8 = {0, 0, 0, 0, 0, 0, 0, 0};
    if (node < n) {
      short8 raw = *(const short8*)(xnb + (size_t)node * HID + c0);
      float vals[8];
      #pragma unroll
      for (int j = 0; j < 8; j++) vals[j] = bf2f((unsigned short)raw[j]);
      float sum = 0.f;
      #pragma unroll
      for (int j = 0; j < 8; j++) sum += vals[j];
      sum += __shfl_xor(sum, 8); sum += __shfl_xor(sum, 4);
      sum += __shfl_xor(sum, 2); sum += __shfl_xor(sum, 1);
      float mu = sum * (1.f / 128.f);
      float sq = 0.f;
      #pragma unroll
      for (int j = 0; j < 8; j++) { float d = vals[j] - mu; sq += d * d; }
      sq += __shfl_xor(sq, 8); sq += __shfl_xor(sq, 4);
      sq += __shfl_xor(sq, 2); sq += __shfl_xor(sq, 1);
      float rstd = rsqrtf(sq * (1.f / 128.f) + 1e-5f);
      #pragma unroll
      for (int j = 0; j < 8; j++)
        h8[j] = (short)f2bf((vals[j] - mu) * rstd * gv[j] + bv2[j]);
    }
    *(short8*)&lnA[nl][(gl ^ (nl & 7)) * 8] = h8;
  }
  __syncthreads();
  int w = tid >> 6, lane = tid & 63;
  int lg = lane >> 4, ll = lane & 15;
  int swz = (ll & 7) << 1;  // tS granule XOR (node = nt*16+ll -> node&7 = ll&7)
  bool ok0 = (node0 + ll) < n, ok1 = (node0 + 16 + ll) < n;
  // ---- GEMM1: D[j][node]; wave w owns j-tiles [w*4, w*4+4), both node-tiles
  // weight frags preloaded 2 j-tiles at a time (8 frags per latency window)
  {
    short8 bfr1[2][4];
    #pragma unroll
    for (int nt = 0; nt < 2; nt++) {
      int arow = nt * 16 + ll;
      #pragma unroll
      for (int kt = 0; kt < 4; kt++)
        bfr1[nt][kt] = *(const short8*)&lnA[arow][((kt * 4 + lg) ^ (ll & 7)) * 8];
    }
    #pragma unroll
    for (int jp = 0; jp < 2; jp++) {
      short8 af[2][4];
      #pragma unroll
      for (int j2 = 0; j2 < 2; j2++) {
        int jt = w * 4 + jp * 2 + j2;
        const unsigned short* wrow = w1b + (size_t)(jt * 16 + ll) * 128 + lg * 8;
        #pragma unroll
        for (int kt = 0; kt < 4; kt++) af[j2][kt] = *(const short8*)(wrow + kt * 32);
      }
      #pragma unroll
      for (int j2 = 0; j2 < 2; j2++) {
        int jt = w * 4 + jp * 2 + j2;
        f32x4 acc[2];
        acc[0] = (f32x4){0.f, 0.f, 0.f, 0.f};
        acc[1] = (f32x4){0.f, 0.f, 0.f, 0.f};
        #pragma unroll
        for (int kt = 0; kt < 4; kt++) {
          acc[0] = __builtin_amdgcn_mfma_f32_16x16x32_bf16(af[j2][kt], bfr1[0][kt], acc[0], 0, 0, 0);
          acc[1] = __builtin_amdgcn_mfma_f32_16x16x32_bf16(af[j2][kt], bfr1[1][kt], acc[1], 0, 0, 0);
        }
        float4 bj = *(const float4*)(b1 + jt * 16 + lg * 4);
        int gr = jt * 4 + lg;  // logical 8B granule (4 consecutive j)
        #pragma unroll
        for (int nt = 0; nt < 2; nt++) {
          int nl = nt * 16 + ll;
          ushort4 o;
          o.x = f2bf(fmaxf(acc[nt][0] + bj.x, 0.f));
          o.y = f2bf(fmaxf(acc[nt][1] + bj.y, 0.f));
          o.z = f2bf(fmaxf(acc[nt][2] + bj.z, 0.f));
          o.w = f2bf(fmaxf(acc[nt][3] + bj.w, 0.f));
          *(ushort4*)&tsf[nl * 512 + (gr ^ swz) * 4] = o;
        }
      }
    }
  }
  __syncthreads();
  // ---- GEMM2: D[c][node]; wave w owns c-tile w, both node-tiles ------------
  // weight frags preloaded 8 at a time (2 latency windows over kt=16)
  {
    int ct = w;
    f32x4 acc[2];
    acc[0] = (f32x4){0.f, 0.f, 0.f, 0.f};
    acc[1] = (f32x4){0.f, 0.f, 0.f, 0.f};
    const unsigned short* wrow = w2b + (size_t)(ct * 16 + ll) * 512 + lg * 8;
    #pragma unroll
    for (int h = 0; h < 2; h++) {
      short8 af[8];
      #pragma unroll
      for (int k8 = 0; k8 < 8; k8++)
        af[k8] = *(const short8*)(wrow + (h * 8 + k8) * 32);
      #pragma unroll
      for (int k8 = 0; k8 < 8; k8++) {
        int kt = h * 8 + k8;
        int G = kt * 8 + lg * 2;  // logical granule pair base (even)
        short8 b0 = *(const short8*)&tsf[(0 * 16 + ll) * 512 + (G ^ swz) * 4];
        short8 b1f = *(const short8*)&tsf[(1 * 16 + ll) * 512 + (G ^ swz) * 4];
        acc[0] = __builtin_amdgcn_mfma_f32_16x16x32_bf16(af[k8], b0, acc[0], 0, 0, 0);
        acc[1] = __builtin_amdgcn_mfma_f32_16x16x32_bf16(af[k8], b1f, acc[1], 0, 0, 0);
      }
    }
    int c = ct * 16 + lg * 4;
    float4 b2q = *(const float4*)(b2 + c);
    #pragma unroll
    for (int nt = 0; nt < 2; nt++) {
      if (nt == 0 ? !ok0 : !ok1) continue;
      int node = node0 + nt * 16 + ll;
      ushort4 xr = *(const ushort4*)(xnb + (size_t)node * HID + c);
      float4 o;
      o.x = bf2f(xr.x) + acc[nt][0] + b2q.x;
      o.y = bf2f(xr.y) + acc[nt][1] + b2q.y;
      o.z = bf2f(xr.z) + acc[nt][2] + b2q.z;
      o.w = bf2f(xr.w) + acc[nt][3] + b2q.w;
      *(float4*)(out + (size_t)node * HID + c) = o;
    }
  }
}

extern "C" void kernel_launch(void* const* d_in, const int* in_sizes, int n_in,
                              void* d_out, int out_size, void* d_ws, size_t ws_size,
                              hipStream_t stream) {
  const float* x     = (const float*)d_in[0];
  const int*   ei    = (const int*)d_in[1];
  const float* attr  = (const float*)d_in[2];
  const float* ln1_g = (const float*)d_in[3];
  const float* ln1_b = (const float*)d_in[4];
  const float* Wq    = (const float*)d_in[5];
  const float* bq    = (const float*)d_in[6];
  const float* Wk    = (const float*)d_in[7];
  const float* bk    = (const float*)d_in[8];
  const float* Wv    = (const float*)d_in[9];
  const float* bv    = (const float*)d_in[10];
  const float* We    = (const float*)d_in[11];
  const float* Wskip = (const float*)d_in[12];
  const float* bskip = (const float*)d_in[13];
  const float* Wbeta = (const float*)d_in[14];
  const float* ln2_g = (const float*)d_in[15];
  const float* ln2_b = (const float*)d_in[16];
  const float* W1    = (const float*)d_in[17];
  const float* b1    = (const float*)d_in[18];
  const float* W2    = (const float*)d_in[19];
  const float* b2    = (const float*)d_in[20];
  float* out = (float*)d_out;
  float* ws  = (float*)d_ws;

  size_t NH  = (size_t)N_NODES * HID;  // 6.4M elements
  size_t NHf = NH / 2;                 // ushort array size in float units
  unsigned short* sb  = (unsigned short*)ws;             // [N][128] bf16 skip
  unsigned short* xnb = (unsigned short*)(ws + NHf);     // [N][128] bf16 xn
  unsigned short* qb  = (unsigned short*)(ws + 2 * NHf); // [N][128] bf16 q
  unsigned char*  kvb = (unsigned char*)(ws + 3 * NHf);  // [N][256] fp8 chunks
  float* base2 = ws + 3 * NHf + (size_t)N_NODES * 256 / 4;
  int* deg       = (int*)base2;
  int* row_start = deg + N_NODES;
  int* cursor    = row_start + N_NODES;
  // 3*N ints = 150000; pad to 16B boundary (150000 % 4 == 0) -> csr_rec aligned
  uint4* csr_rec = (uint4*)(base2 + 150000);
  unsigned short* wqkvs = (unsigned short*)(base2 + 150000 + (size_t)E_EDGES * 4);
  unsigned short* w1b   = wqkvs + 65536;
  unsigned short* w2b   = w1b + 65536;
  int* bsum = (int*)(w2b + 65536);  // NSB=49 block sums

  wcvt_kernel<<<WCB + NSB, 256, 0, stream>>>(
      (const float4*)Wq, (const float4*)Wk, (const float4*)Wv,
      (const float4*)Wskip, (const float4*)W1, (const float4*)W2,
      wqkvs, w1b, w2b, deg);
  qkvs_kernel<<<2 * NQB, 256, 0, stream>>>(
      x, ln1_g, ln1_b, wqkvs, bq, bk, bv, bskip, qb, kvb, sb, ei, deg, N_NODES);
  scan1_kernel<<<NSB, 256, 0, stream>>>(deg, bsum);
  scan2_kernel<<<NSB, 256, 0, stream>>>(deg, bsum, row_start, cursor);
  scatter_kernel<<<(E_EDGES + 255) / 256, 256, 0, stream>>>(
      ei, (const float4*)attr, cursor, csr_rec);
  gather_kernel<<<(N_NODES * 64 + 255) / 256, 256, 0, stream>>>(
      row_start, deg, csr_rec, We, qb, kvb, x, sb, Wbeta, xnb, N_NODES);
  mlp_kernel<<<(N_NODES + 31) / 32, 512, 0, stream>>>(
      xnb, ln2_g, ln2_b, w1b, b1, w2b, b2, out, N_NODES);
}

// Round 20
// 213.510 us; speedup vs baseline: 1.0644x; 1.0618x over previous
//
#include <hip/hip_runtime.h>

#define N_NODES 50000
#define E_EDGES 800000
#define HID 128
#define NQB 782   // ceil(50000/64) node-tile blocks in the fused qkvs kernel
#define SCAN_BLK 1024
#define NSB 49    // ceil(50000/1024)
#define WCB 192   // wcvt conversion blocks; blocks [WCB, WCB+49) zero deg

typedef __attribute__((ext_vector_type(8))) short short8;
typedef __attribute__((ext_vector_type(4))) float f32x4;
typedef __attribute__((ext_vector_type(2))) float f32x2;

static __device__ __forceinline__ unsigned short f2bf(float f) {
  unsigned int u = __builtin_bit_cast(unsigned int, f);
  u += 0x7fff + ((u >> 16) & 1);  // round-to-nearest-even
  return (unsigned short)(u >> 16);
}
static __device__ __forceinline__ float bf2f(unsigned short u) {
  return __builtin_bit_cast(float, (unsigned int)u << 16);
}
static __device__ __forceinline__ float bf_lo(unsigned u) {  // low bf16 -> f32
  return __builtin_bit_cast(float, u << 16);
}
static __device__ __forceinline__ float bf_hi(unsigned u) {  // high bf16 -> f32
  return __builtin_bit_cast(float, u & 0xffff0000u);
}
static __device__ __forceinline__ unsigned short pk_fp8(float a, float b) {
  return (unsigned short)(__builtin_amdgcn_cvt_pk_fp8_f32(a, b, 0, false) & 0xffff);
}

// ---- weight conversion fp32 -> bf16 + deg zeroing ---------------------------
__global__ __launch_bounds__(256) void wcvt_kernel(
    const float4* __restrict__ Wq, const float4* __restrict__ Wk,
    const float4* __restrict__ Wv, const float4* __restrict__ Ws,
    const float4* __restrict__ W1, const float4* __restrict__ W2,
    unsigned short* __restrict__ wqkvs, unsigned short* __restrict__ w1b,
    unsigned short* __restrict__ w2b, int* __restrict__ deg)
{
  if (blockIdx.x >= WCB) {  // ---- deg zero path ----
    int idx = ((blockIdx.x - WCB) * 256 + threadIdx.x) * 4;
    if (idx + 3 < N_NODES) *(int4*)(deg + idx) = (int4){0, 0, 0, 0};
    else {
      for (int t = 0; t < 4; t++)
        if (idx + t < N_NODES) deg[idx + t] = 0;
    }
    return;
  }
  int i = blockIdx.x * 256 + threadIdx.x;  // [0, 49152) float4 groups
  const float4* src;
  unsigned short* dst;
  if (i < 16384) {
    int part = i >> 12;
    src = ((part == 0) ? Wq : (part == 1) ? Wk : (part == 2) ? Wv : Ws) + (i & 4095);
    dst = wqkvs + i * 4;
  } else if (i < 32768) {
    src = W1 + (i - 16384); dst = w1b + (size_t)(i - 16384) * 4;
  } else {
    src = W2 + (i - 32768); dst = w2b + (size_t)(i - 32768) * 4;
  }
  float4 v = *src;
  ushort4 o;
  o.x = f2bf(v.x); o.y = f2bf(v.y); o.z = f2bf(v.z); o.w = f2bf(v.w);
  *(ushort4*)dst = o;
}

// ---- fused [LN1 + QKVS projection via bf16 MFMA | degree count] -------------
// kv layout: [node][32 chunks of 8B]; chunk c = {k[4c..4c+3] | v[4c..4c+3]}.
__global__ __launch_bounds__(256) void qkvs_kernel(
    const float* __restrict__ x,
    const float* __restrict__ g1, const float* __restrict__ bln,
    const unsigned short* __restrict__ wqkvs,
    const float* __restrict__ bq, const float* __restrict__ bk,
    const float* __restrict__ bv, const float* __restrict__ bs,
    unsigned short* __restrict__ qb, unsigned char* __restrict__ kvb,
    unsigned short* __restrict__ sb,
    const int* __restrict__ ei, int* __restrict__ deg, int n)
{
  if (blockIdx.x >= NQB) {  // ---- degree count path ----
    for (int e = (blockIdx.x - NQB) * 256 + threadIdx.x; e < E_EDGES;
         e += NQB * 256)
      atomicAdd(deg + ei[E_EDGES + e], 1);
    return;
  }
  __shared__ short lnA[64][128];
  int node0 = blockIdx.x * 64;
  int tid = threadIdx.x;
  int g = tid >> 4, gl = tid & 15, c0 = gl * 8;
  {
    float gv[8], bv2[8];
    *(float4*)&gv[0] = *(const float4*)(g1 + c0);
    *(float4*)&gv[4] = *(const float4*)(g1 + c0 + 4);
    *(float4*)&bv2[0] = *(const float4*)(bln + c0);
    *(float4*)&bv2[4] = *(const float4*)(bln + c0 + 4);
    for (int ni = 0; ni < 4; ni++) {
      int nl = ni * 16 + g;
      int node = node0 + nl;
      short8 h8 = {0, 0, 0, 0, 0, 0, 0, 0};
      if (node < n) {
        float vals[8];
        const float* row = x + (size_t)node * HID + c0;
        *(float4*)&vals[0] = *(const float4*)row;
        *(float4*)&vals[4] = *(const float4*)(row + 4);
        float sum = 0.f;
        #pragma unroll
        for (int j = 0; j < 8; j++) sum += vals[j];
        sum += __shfl_xor(sum, 8); sum += __shfl_xor(sum, 4);
        sum += __shfl_xor(sum, 2); sum += __shfl_xor(sum, 1);
        float mu = sum * (1.f / 128.f);
        float sq = 0.f;
        #pragma unroll
        for (int j = 0; j < 8; j++) { float d = vals[j] - mu; sq += d * d; }
        sq += __shfl_xor(sq, 8); sq += __shfl_xor(sq, 4);
        sq += __shfl_xor(sq, 2); sq += __shfl_xor(sq, 1);
        float rstd = rsqrtf(sq * (1.f / 128.f) + 1e-5f);
        #pragma unroll
        for (int j = 0; j < 8; j++)
          h8[j] = (short)f2bf((vals[j] - mu) * rstd * gv[j] + bv2[j]);
      }
      *(short8*)&lnA[nl][(gl ^ (nl & 7)) * 8] = h8;
    }
  }
  __syncthreads();
  int w = tid >> 6, lane = tid & 63;
  int lg = lane >> 4, ll = lane & 15;
  short8 bfr[4][4];
  #pragma unroll
  for (int nt = 0; nt < 4; nt++) {
    int arow = nt * 16 + ll;
    #pragma unroll
    for (int kt = 0; kt < 4; kt++)
      bfr[nt][kt] = *(const short8*)&lnA[arow][((kt * 4 + lg) ^ (ll & 7)) * 8];
  }
  const float* biasp = (w == 0) ? bq : (w == 1) ? bk : (w == 2) ? bv : bs;
  bool ok[4];
  #pragma unroll
  for (int nt = 0; nt < 4; nt++) ok[nt] = (node0 + nt * 16 + ll) < n;
  for (int ci = 0; ci < 8; ci++) {
    const unsigned short* wrow = wqkvs + (size_t)(w * 128 + ci * 16 + ll) * 128 + lg * 8;
    short8 af[4];
    #pragma unroll
    for (int kt = 0; kt < 4; kt++) af[kt] = *(const short8*)(wrow + kt * 32);
    f32x4 acc[4];
    #pragma unroll
    for (int nt = 0; nt < 4; nt++) acc[nt] = (f32x4){0.f, 0.f, 0.f, 0.f};
    #pragma unroll
    for (int kt = 0; kt < 4; kt++)
      #pragma unroll
      for (int nt = 0; nt < 4; nt++)
        acc[nt] = __builtin_amdgcn_mfma_f32_16x16x32_bf16(af[kt], bfr[nt][kt], acc[nt], 0, 0, 0);
    int jj = ci * 16 + lg * 4;  // 4 consecutive channels within this matrix
    float4 bq4 = *(const float4*)(biasp + jj);
    #pragma unroll
    for (int nt = 0; nt < 4; nt++) {
      if (!ok[nt]) continue;
      int node = node0 + nt * 16 + ll;
      float v0 = acc[nt][0] + bq4.x, v1 = acc[nt][1] + bq4.y;
      float v2 = acc[nt][2] + bq4.z, v3 = acc[nt][3] + bq4.w;
      if (w == 0 || w == 3) {
        ushort4 o;
        o.x = f2bf(v0); o.y = f2bf(v1); o.z = f2bf(v2); o.w = f2bf(v3);
        *(ushort4*)((w == 0 ? qb : sb) + (size_t)node * HID + jj) = o;
      } else {
        // chunk (jj>>2): k-word at +0, v-word at +4
        unsigned word = (unsigned)pk_fp8(v0, v1) | ((unsigned)pk_fp8(v2, v3) << 16);
        *(unsigned*)(kvb + (unsigned)node * 256 + (jj >> 2) * 8 + (w == 1 ? 0 : 4)) = word;
      }
    }
  }
}

// -------- CSR build: per-block degree sums (coalesced int4 reads) ------------
__global__ __launch_bounds__(256) void scan1_kernel(
    const int* __restrict__ deg, int* __restrict__ bsum)
{
  __shared__ int wsum[4];
  int b = blockIdx.x;
  int idx = b * SCAN_BLK + threadIdx.x * 4;
  int4 v = {0, 0, 0, 0};
  if (idx + 3 < N_NODES) v = *(const int4*)(deg + idx);
  else {
    if (idx     < N_NODES) v.x = deg[idx];
    if (idx + 1 < N_NODES) v.y = deg[idx + 1];
    if (idx + 2 < N_NODES) v.z = deg[idx + 2];
    if (idx + 3 < N_NODES) v.w = deg[idx + 3];
  }
  int s = v.x + v.y + v.z + v.w;
  for (int m = 1; m < 64; m <<= 1) s += __shfl_xor(s, m);
  int lane = threadIdx.x & 63, w = threadIdx.x >> 6;
  if (lane == 0) wsum[w] = s;
  __syncthreads();
  if (threadIdx.x == 0) bsum[b] = wsum[0] + wsum[1] + wsum[2] + wsum[3];
}

// -------- CSR build: block-local exclusive scan + global offset --------------
__global__ __launch_bounds__(256) void scan2_kernel(
    const int* __restrict__ deg, const int* __restrict__ bsum,
    int* __restrict__ row_start, int* __restrict__ cursor)
{
  __shared__ int boff_s;
  __shared__ int wsum[4];
  int b = blockIdx.x;
  int tid = threadIdx.x;
  int lane = tid & 63, w = tid >> 6;
  if (tid < 64) {  // block offset = sum of bsum[0..b)  (NSB=49 < 64)
    int v = (lane < b) ? bsum[lane] : 0;
    for (int m = 1; m < 64; m <<= 1) v += __shfl_xor(v, m);
    if (lane == 0) boff_s = v;
  }
  int idx = b * SCAN_BLK + tid * 4;
  int4 v = {0, 0, 0, 0};
  if (idx + 3 < N_NODES) v = *(const int4*)(deg + idx);
  else {
    if (idx     < N_NODES) v.x = deg[idx];
    if (idx + 1 < N_NODES) v.y = deg[idx + 1];
    if (idx + 2 < N_NODES) v.z = deg[idx + 2];
    if (idx + 3 < N_NODES) v.w = deg[idx + 3];
  }
  int ts = v.x + v.y + v.z + v.w;
  int incl = ts;
  for (int m = 1; m < 64; m <<= 1) {
    int t = __shfl_up(incl, m);
    if (lane >= m) incl += t;
  }
  if (lane == 63) wsum[w] = incl;
  __syncthreads();
  int woff = 0;
  for (int i = 0; i < w; i++) woff += wsum[i];
  int excl = boff_s + woff + incl - ts;
  int4 o;
  o.x = excl;
  o.y = excl + v.x;
  o.z = excl + v.x + v.y;
  o.w = excl + v.x + v.y + v.z;
  if (idx + 3 < N_NODES) {
    *(int4*)(row_start + idx) = o;
    *(int4*)(cursor + idx) = o;
  } else {
    if (idx     < N_NODES) { row_start[idx]     = o.x; cursor[idx]     = o.x; }
    if (idx + 1 < N_NODES) { row_start[idx + 1] = o.y; cursor[idx + 1] = o.y; }
    if (idx + 2 < N_NODES) { row_start[idx + 2] = o.z; cursor[idx + 2] = o.z; }
    if (idx + 3 < N_NODES) { row_start[idx + 3] = o.w; cursor[idx + 3] = o.w; }
  }
}

// -------- CSR build: scatter unified 16B records -----------------------------
// rec = {src_byteoff:int, attr01:2xbf16, attr23:2xbf16, pad}
__global__ __launch_bounds__(256) void scatter_kernel(
    const int* __restrict__ ei, const float4* __restrict__ attr,
    int* __restrict__ cursor, uint4* __restrict__ csr_rec)
{
  int e = blockIdx.x * 256 + threadIdx.x;
  if (e >= E_EDGES) return;
  int dst = ei[E_EDGES + e];
  float4 a4 = attr[e];
  int pos = atomicAdd(cursor + dst, 1);
  uint4 rec;
  rec.x = (unsigned)(ei[e] * 256);  // pre-multiplied byte offset into kvb
  rec.y = (unsigned)f2bf(a4.x) | ((unsigned)f2bf(a4.y) << 16);
  rec.z = (unsigned)f2bf(a4.z) | ((unsigned)f2bf(a4.w) << 16);
  rec.w = 0u;
  csr_rec[pos] = rec;
}

// -------- Gather + combine: 1 wave per dst node, 2 edge slots x 32 lanes -----
// q·(k+e) = q·k + (q^T We)·attr ;  Σ a_j e_j = We (Σ a_j attr_j).
// Lane = 4 channels (8B kv chunk); slot s = lane>>5 handles edge j+s.
// Unified 16B records scalarized via readfirstlane -> s_load_dwordx4; attr
// decoded from bf16 pairs; 2-deep SGPR record pipeline; kv on vector path.
__global__ __launch_bounds__(256) void gather_kernel(
    const int* __restrict__ row_start, const int* __restrict__ deg,
    const uint4* __restrict__ csr_rec,
    const float* __restrict__ We,
    const unsigned short* __restrict__ qb, const unsigned char* __restrict__ kvb,
    const float* __restrict__ x, const unsigned short* __restrict__ sb,
    const float* __restrict__ Wb, unsigned short* __restrict__ xnb, int n)
{
  int node = (blockIdx.x * blockDim.x + threadIdx.x) >> 6;
  if (node >= n) return;
  int nodeu = __builtin_amdgcn_readfirstlane(node);
  int lane = threadIdx.x & 63;
  int hl = lane & 31;   // half-lane: channel chunk
  int s  = lane >> 5;   // edge slot
  int c0 = hl * 4;      // 4 channels per lane
  const unsigned short* qrow = qb + (size_t)nodeu * HID;
  ushort4 q4 = *(const ushort4*)(qrow + c0);
  float q0 = bf2f(q4.x), q1 = bf2f(q4.y), q2 = bf2f(q4.z), q3 = bf2f(q4.w);
  float4 wr0 = *(const float4*)(We + (c0 + 0) * 4);
  float4 wr1 = *(const float4*)(We + (c0 + 1) * 4);
  float4 wr2 = *(const float4*)(We + (c0 + 2) * 4);
  float4 wr3 = *(const float4*)(We + (c0 + 3) * 4);
  float qwe0 = q0 * wr0.x + q1 * wr1.x + q2 * wr2.x + q3 * wr3.x;
  float qwe1 = q0 * wr0.y + q1 * wr1.y + q2 * wr2.y + q3 * wr3.y;
  float qwe2 = q0 * wr0.z + q1 * wr1.z + q2 * wr2.z + q3 * wr3.z;
  float qwe3 = q0 * wr0.w + q1 * wr1.w + q2 * wr2.w + q3 * wr3.w;
  qwe0 += __shfl_xor(qwe0, 1); qwe0 += __shfl_xor(qwe0, 2); qwe0 += __shfl_xor(qwe0, 4);
  qwe1 += __shfl_xor(qwe1, 1); qwe1 += __shfl_xor(qwe1, 2); qwe1 += __shfl_xor(qwe1, 4);
  qwe2 += __shfl_xor(qwe2, 1); qwe2 += __shfl_xor(qwe2, 2); qwe2 += __shfl_xor(qwe2, 4);
  qwe3 += __shfl_xor(qwe3, 1); qwe3 += __shfl_xor(qwe3, 2); qwe3 += __shfl_xor(qwe3, 4);
  const float s2 = 0.17677669529663687f * 1.4426950408889634f;  // /sqrt(32)*log2e
  float q0s = q0 * s2, q1s = q1 * s2, q2s = q2 * s2, q3s = q3 * s2;
  qwe0 *= s2; qwe1 *= s2; qwe2 *= s2; qwe3 *= s2;
  float acc0 = 0.f, acc1 = 0.f, acc2 = 0.f, acc3 = 0.f, den = 0.f;
  float aat0 = 0.f, aat1 = 0.f, aat2 = 0.f, aat3 = 0.f;
  int rs = row_start[nodeu];
  int cnt = deg[nodeu];
  int re = rs + cnt;
  unsigned off = (unsigned)hl * 8;
  // current records (slots rs, rs+1) in SGPRs
  int i0 = __builtin_amdgcn_readfirstlane(min(rs,     E_EDGES - 1));
  int i1 = __builtin_amdgcn_readfirstlane(min(rs + 1, E_EDGES - 1));
  uint4 rC0 = csr_rec[i0];
  uint4 rC1 = csr_rec[i1];
  unsigned srcsel = s ? rC1.x : rC0.x;
  uint2 kvc = *(const uint2*)(kvb + srcsel + off);
  float4 ac;
  ac.x = s ? bf_lo(rC1.y) : bf_lo(rC0.y);
  ac.y = s ? bf_hi(rC1.y) : bf_hi(rC0.y);
  ac.z = s ? bf_lo(rC1.z) : bf_lo(rC0.z);
  ac.w = s ? bf_hi(rC1.z) : bf_hi(rC0.z);
  // next records (slots rs+2, rs+3) in SGPRs
  int i2 = __builtin_amdgcn_readfirstlane(min(rs + 2, E_EDGES - 1));
  int i3 = __builtin_amdgcn_readfirstlane(min(rs + 3, E_EDGES - 1));
  uint4 rN0 = csr_rec[i2];
  uint4 rN1 = csr_rec[i3];
  for (int j = rs; j < re; j += 2) {
    // issue next kv load (address from SGPR-resident records)
    unsigned srcn = s ? rN1.x : rN0.x;
    uint2 kvn = *(const uint2*)(kvb + srcn + off);
    float4 an;
    an.x = s ? bf_lo(rN1.y) : bf_lo(rN0.y);
    an.y = s ? bf_hi(rN1.y) : bf_hi(rN0.y);
    an.z = s ? bf_lo(rN1.z) : bf_lo(rN0.z);
    an.w = s ? bf_hi(rN1.z) : bf_hi(rN0.z);
    // issue scalar loads for the pair after next
    int p0 = __builtin_amdgcn_readfirstlane(min(j + 4, E_EDGES - 1));
    int p1 = __builtin_amdgcn_readfirstlane(min(j + 5, E_EDGES - 1));
    uint4 rP0 = csr_rec[p0];
    uint4 rP1 = csr_rec[p1];
    // compute on current
    f32x2 k01 = __builtin_amdgcn_cvt_pk_f32_fp8((int)kvc.x, false);
    f32x2 k23 = __builtin_amdgcn_cvt_pk_f32_fp8((int)kvc.x, true);
    float dot = q0s * k01.x + q1s * k01.y + q2s * k23.x + q3s * k23.y;
    dot += __shfl_xor(dot, 1);
    dot += __shfl_xor(dot, 2);
    dot += __shfl_xor(dot, 4);
    float e = exp2f(dot + qwe0 * ac.x + qwe1 * ac.y + qwe2 * ac.z + qwe3 * ac.w);
    e = (j + s < re) ? e : 0.f;  // slot validity (max-free softmax)
    den += e;
    aat0 += e * ac.x; aat1 += e * ac.y;
    aat2 += e * ac.z; aat3 += e * ac.w;
    f32x2 v01 = __builtin_amdgcn_cvt_pk_f32_fp8((int)kvc.y, false);
    f32x2 v23 = __builtin_amdgcn_cvt_pk_f32_fp8((int)kvc.y, true);
    acc0 += e * v01.x; acc1 += e * v01.y;
    acc2 += e * v23.x; acc3 += e * v23.y;
    // rotate
    kvc = kvn; ac = an;
    rN0 = rP0; rN1 = rP1;
  }
  // ---- combine the 2 edge slots ----
  acc0 += __shfl_xor(acc0, 32); acc1 += __shfl_xor(acc1, 32);
  acc2 += __shfl_xor(acc2, 32); acc3 += __shfl_xor(acc3, 32);
  den  += __shfl_xor(den, 32);
  aat0 += __shfl_xor(aat0, 32); aat1 += __shfl_xor(aat1, 32);
  aat2 += __shfl_xor(aat2, 32); aat3 += __shfl_xor(aat3, 32);
  float inv = 1.0f / (den + 1e-16f);
  float o0 = (acc0 + wr0.x * aat0 + wr0.y * aat1 + wr0.z * aat2 + wr0.w * aat3) * inv;
  float o1 = (acc1 + wr1.x * aat0 + wr1.y * aat1 + wr1.z * aat2 + wr1.w * aat3) * inv;
  float o2 = (acc2 + wr2.x * aat0 + wr2.y * aat1 + wr2.z * aat2 + wr2.w * aat3) * inv;
  float o3 = (acc3 + wr3.x * aat0 + wr3.y * aat1 + wr3.z * aat2 + wr3.w * aat3) * inv;
  // ---- fused combine: beta gate + first residual ----
  ushort4 sp4 = *(const ushort4*)(sb + (size_t)nodeu * HID + c0);
  float sk0 = bf2f(sp4.x), sk1 = bf2f(sp4.y), sk2 = bf2f(sp4.z), sk3 = bf2f(sp4.w);
  float4 wbA = *(const float4*)(Wb + c0);
  float4 wbB = *(const float4*)(Wb + 128 + c0);
  float4 wbC = *(const float4*)(Wb + 256 + c0);
  float bpart = o0 * (wbA.x + wbC.x) + sk0 * (wbB.x - wbC.x) +
                o1 * (wbA.y + wbC.y) + sk1 * (wbB.y - wbC.y) +
                o2 * (wbA.z + wbC.z) + sk2 * (wbB.z - wbC.z) +
                o3 * (wbA.w + wbC.w) + sk3 * (wbB.w - wbC.w);
  bpart += __shfl_xor(bpart, 1); bpart += __shfl_xor(bpart, 2);
  bpart += __shfl_xor(bpart, 4); bpart += __shfl_xor(bpart, 8);
  bpart += __shfl_xor(bpart, 16);  // sum over 32 lanes (each half has full sum)
  float beta = 1.0f / (1.0f + exp2f(-bpart * 1.4426950408889634f));
  if (lane < 32) {
    float4 xv = *(const float4*)(x + (size_t)nodeu * HID + c0);
    ushort4 o4;
    o4.x = f2bf(xv.x + beta * sk0 + (1.0f - beta) * o0);
    o4.y = f2bf(xv.y + beta * sk1 + (1.0f - beta) * o1);
    o4.z = f2bf(xv.z + beta * sk2 + (1.0f - beta) * o2);
    o4.w = f2bf(xv.w + beta * sk3 + (1.0f - beta) * o3);
    *(ushort4*)(xnb + (size_t)nodeu * HID + c0) = o4;
  }
}

// ---- fused LN2 + MLP (GEMM1 relu GEMM2) via bf16 MFMA + residual ------------
// 64-node tile, 512 threads (8 waves), 80KB LDS -> 2 blocks/CU. Halves the
// per-block weight stream (W1+W2 read once per 64 nodes instead of per 32)
// and doubles MFMA per weight fragment (4 node-tiles per wave).
__global__ __launch_bounds__(512) void mlp_kernel(
    const unsigned short* __restrict__ xnb,
    const float* __restrict__ g2, const float* __restrict__ b2ln,
    const unsigned short* __restrict__ w1b, const float* __restrict__ b1,
    const unsigned short* __restrict__ w2b, const float* __restrict__ b2,
    float* __restrict__ out, int n)
{
  __shared__ short lnA[64][128];
  __shared__ short tS[64][512];
  short* tsf = &tS[0][0];
  int node0 = blockIdx.x * 64;
  int tid = threadIdx.x;
  int g = tid >> 4, gl = tid & 15, c0 = gl * 8;
  {
    // 512 threads: 32 rows x 16 threads per pass, 2 passes
    float gv[8], bv2[8];
    *(float4*)&gv[0] = *(const float4*)(g2 + c0);
    *(float4*)&gv[4] = *(const float4*)(g2 + c0 + 4);
    *(float4*)&bv2[0] = *(const float4*)(b2ln + c0);
    *(float4*)&bv2[4] = *(const float4*)(b2ln + c0 + 4);
    #pragma unroll
    for (int ni = 0; ni < 2; ni++) {
      int nl = ni * 32 + g;
      int node = node0 + nl;
      short8 h8 = {0, 0, 0, 0, 0, 0, 0, 0};
      if (node < n) {
        short8 raw = *(const short8*)(xnb + (size_t)node * HID + c0);
        float vals[8];
        #pragma unroll
        for (int j = 0; j < 8; j++) vals[j] = bf2f((unsigned short)raw[j]);
        float sum = 0.f;
        #pragma unroll
        for (int j = 0; j < 8; j++) sum += vals[j];
        sum += __shfl_xor(sum, 8); sum += __shfl_xor(sum, 4);
        sum += __shfl_xor(sum, 2); sum += __shfl_xor(sum, 1);
        float mu = sum * (1.f / 128.f);
        float sq = 0.f;
        #pragma unroll
        for (int j = 0; j < 8; j++) { float d = vals[j] - mu; sq += d * d; }
        sq += __shfl_xor(sq, 8); sq += __shfl_xor(sq, 4);
        sq += __shfl_xor(sq, 2); sq += __shfl_xor(sq, 1);
        float rstd = rsqrtf(sq * (1.f / 128.f) + 1e-5f);
        #pragma unroll
        for (int j = 0; j < 8; j++)
          h8[j] = (short)f2bf((vals[j] - mu) * rstd * gv[j] + bv2[j]);
      }
      *(short8*)&lnA[nl][(gl ^ (nl & 7)) * 8] = h8;
    }
  }
  __syncthreads();
  int w = tid >> 6, lane = tid & 63;
  int lg = lane >> 4, ll = lane & 15;
  int swz = (ll & 7) << 1;  // tS granule XOR (node = nt*16+ll -> node&7 = ll&7)
  bool ok[4];
  #pragma unroll
  for (int nt = 0; nt < 4; nt++) ok[nt] = (node0 + nt * 16 + ll) < n;
  // ---- GEMM1: D[j][node]; wave w owns j-tiles [w*4, w*4+4), 4 node-tiles ----
  {
    short8 bfr1[4][4];
    #pragma unroll
    for (int nt = 0; nt < 4; nt++) {
      int arow = nt * 16 + ll;
      #pragma unroll
      for (int kt = 0; kt < 4; kt++)
        bfr1[nt][kt] = *(const short8*)&lnA[arow][((kt * 4 + lg) ^ (ll & 7)) * 8];
    }
    for (int ji = 0; ji < 4; ji++) {
      int jt = w * 4 + ji;
      const unsigned short* wrow = w1b + (size_t)(jt * 16 + ll) * 128 + lg * 8;
      short8 af[4];
      #pragma unroll
      for (int kt = 0; kt < 4; kt++) af[kt] = *(const short8*)(wrow + kt * 32);
      f32x4 acc[4];
      #pragma unroll
      for (int nt = 0; nt < 4; nt++) acc[nt] = (f32x4){0.f, 0.f, 0.f, 0.f};
      #pragma unroll
      for (int kt = 0; kt < 4; kt++)
        #pragma unroll
        for (int nt = 0; nt < 4; nt++)
          acc[nt] = __builtin_amdgcn_mfma_f32_16x16x32_bf16(af[kt], bfr1[nt][kt], acc[nt], 0, 0, 0);
      float4 bj = *(const float4*)(b1 + jt * 16 + lg * 4);
      int gr = jt * 4 + lg;  // logical 8B granule (4 consecutive j)
      #pragma unroll
      for (int nt = 0; nt < 4; nt++) {
        int nl = nt * 16 + ll;
        ushort4 o;
        o.x = f2bf(fmaxf(acc[nt][0] + bj.x, 0.f));
        o.y = f2bf(fmaxf(acc[nt][1] + bj.y, 0.f));
        o.z = f2bf(fmaxf(acc[nt][2] + bj.z, 0.f));
        o.w = f2bf(fmaxf(acc[nt][3] + bj.w, 0.f));
        *(ushort4*)&tsf[nl * 512 + (gr ^ swz) * 4] = o;
      }
    }
  }
  __syncthreads();
  // ---- GEMM2: D[c][node]; wave w owns c-tile w, 4 node-tiles ---------------
  {
    int ct = w;
    f32x4 acc[4];
    #pragma unroll
    for (int nt = 0; nt < 4; nt++) acc[nt] = (f32x4){0.f, 0.f, 0.f, 0.f};
    const unsigned short* wrow = w2b + (size_t)(ct * 16 + ll) * 512 + lg * 8;
    #pragma unroll
    for (int kt = 0; kt < 16; kt++) {
      short8 af = *(const short8*)(wrow + kt * 32);
      int G = kt * 8 + lg * 2;  // logical granule pair base (even)
      #pragma unroll
      for (int nt = 0; nt < 4; nt++) {
        short8 bfrag = *(const short8*)&tsf[(nt * 16 + ll) * 512 + (G ^ swz) * 4];
        acc[nt] = __builtin_amdgcn_mfma_f32_16x16x32_bf16(af, bfrag, acc[nt], 0, 0, 0);
      }
    }
    int c = ct * 16 + lg * 4;
    float4 b2q = *(const float4*)(b2 + c);
    #pragma unroll
    for (int nt = 0; nt < 4; nt++) {
      if (!ok[nt]) continue;
      int node = node0 + nt * 16 + ll;
      ushort4 xr = *(const ushort4*)(xnb + (size_t)node * HID + c);
      float4 o;
      o.x = bf2f(xr.x) + acc[nt][0] + b2q.x;
      o.y = bf2f(xr.y) + acc[nt][1] + b2q.y;
      o.z = bf2f(xr.z) + acc[nt][2] + b2q.z;
      o.w = bf2f(xr.w) + acc[nt][3] + b2q.w;
      *(float4*)(out + (size_t)node * HID + c) = o;
    }
  }
}

extern "C" void kernel_launch(void* const* d_in, const int* in_sizes, int n_in,
                              void* d_out, int out_size, void* d_ws, size_t ws_size,
                              hipStream_t stream) {
  const float* x     = (const float*)d_in[0];
  const int*   ei    = (const int*)d_in[1];
  const float* attr  = (const float*)d_in[2];
  const float* ln1_g = (const float*)d_in[3];
  const float* ln1_b = (const float*)d_in[4];
  const float* Wq    = (const float*)d_in[5];
  const float* bq    = (const float*)d_in[6];
  const float* Wk    = (const float*)d_in[7];
  const float* bk    = (const float*)d_in[8];
  const float* Wv    = (const float*)d_in[9];
  const float* bv    = (const float*)d_in[10];
  const float* We    = (const float*)d_in[11];
  const float* Wskip = (const float*)d_in[12];
  const float* bskip = (const float*)d_in[13];
  const float* Wbeta = (const float*)d_in[14];
  const float* ln2_g = (const float*)d_in[15];
  const float* ln2_b = (const float*)d_in[16];
  const float* W1    = (const float*)d_in[17];
  const float* b1    = (const float*)d_in[18];
  const float* W2    = (const float*)d_in[19];
  const float* b2    = (const float*)d_in[20];
  float* out = (float*)d_out;
  float* ws  = (float*)d_ws;

  size_t NH  = (size_t)N_NODES * HID;  // 6.4M elements
  size_t NHf = NH / 2;                 // ushort array size in float units
  unsigned short* sb  = (unsigned short*)ws;             // [N][128] bf16 skip
  unsigned short* xnb = (unsigned short*)(ws + NHf);     // [N][128] bf16 xn
  unsigned short* qb  = (unsigned short*)(ws + 2 * NHf); // [N][128] bf16 q
  unsigned char*  kvb = (unsigned char*)(ws + 3 * NHf);  // [N][256] fp8 chunks
  float* base2 = ws + 3 * NHf + (size_t)N_NODES * 256 / 4;
  int* deg       = (int*)base2;
  int* row_start = deg + N_NODES;
  int* cursor    = row_start + N_NODES;
  // 3*N ints = 150000; pad to 16B boundary (150000 % 4 == 0) -> csr_rec aligned
  uint4* csr_rec = (uint4*)(base2 + 150000);
  unsigned short* wqkvs = (unsigned short*)(base2 + 150000 + (size_t)E_EDGES * 4);
  unsigned short* w1b   = wqkvs + 65536;
  unsigned short* w2b   = w1b + 65536;
  int* bsum = (int*)(w2b + 65536);  // NSB=49 block sums

  wcvt_kernel<<<WCB + NSB, 256, 0, stream>>>(
      (const float4*)Wq, (const float4*)Wk, (const float4*)Wv,
      (const float4*)Wskip, (const float4*)W1, (const float4*)W2,
      wqkvs, w1b, w2b, deg);
  qkvs_kernel<<<2 * NQB, 256, 0, stream>>>(
      x, ln1_g, ln1_b, wqkvs, bq, bk, bv, bskip, qb, kvb, sb, ei, deg, N_NODES);
  scan1_kernel<<<NSB, 256, 0, stream>>>(deg, bsum);
  scan2_kernel<<<NSB, 256, 0, stream>>>(deg, bsum, row_start, cursor);
  scatter_kernel<<<(E_EDGES + 255) / 256, 256, 0, stream>>>(
      ei, (const float4*)attr, cursor, csr_rec);
  gather_kernel<<<(N_NODES * 64 + 255) / 256, 256, 0, stream>>>(
      row_start, deg, csr_rec, We, qb, kvb, x, sb, Wbeta, xnb, N_NODES);
  mlp_kernel<<<(N_NODES + 63) / 64, 512, 0, stream>>>(
      xnb, ln2_g, ln2_b, w1b, b1, w2b, b2, out, N_NODES);
}

// Round 21
// 206.614 us; speedup vs baseline: 1.0999x; 1.0334x over previous
//
#include <hip/hip_runtime.h>

#define N_NODES 50000
#define E_EDGES 800000
#define HID 128
#define NQB2 391  // ceil(50000/128) node-tile blocks in the fused qkvs kernel
#define SCAN_BLK 1024
#define NSB 49    // ceil(50000/1024)
#define WCB 192   // wcvt conversion blocks; blocks [WCB, WCB+49) zero deg

typedef __attribute__((ext_vector_type(8))) short short8;
typedef __attribute__((ext_vector_type(4))) float f32x4;
typedef __attribute__((ext_vector_type(2))) float f32x2;

static __device__ __forceinline__ unsigned short f2bf(float f) {
  unsigned int u = __builtin_bit_cast(unsigned int, f);
  u += 0x7fff + ((u >> 16) & 1);  // round-to-nearest-even
  return (unsigned short)(u >> 16);
}
static __device__ __forceinline__ float bf2f(unsigned short u) {
  return __builtin_bit_cast(float, (unsigned int)u << 16);
}
static __device__ __forceinline__ float bf_lo(unsigned u) {  // low bf16 -> f32
  return __builtin_bit_cast(float, u << 16);
}
static __device__ __forceinline__ float bf_hi(unsigned u) {  // high bf16 -> f32
  return __builtin_bit_cast(float, u & 0xffff0000u);
}
static __device__ __forceinline__ unsigned short pk_fp8(float a, float b) {
  return (unsigned short)(__builtin_amdgcn_cvt_pk_fp8_f32(a, b, 0, false) & 0xffff);
}

// ---- weight conversion fp32 -> bf16 + deg zeroing ---------------------------
__global__ __launch_bounds__(256) void wcvt_kernel(
    const float4* __restrict__ Wq, const float4* __restrict__ Wk,
    const float4* __restrict__ Wv, const float4* __restrict__ Ws,
    const float4* __restrict__ W1, const float4* __restrict__ W2,
    unsigned short* __restrict__ wqkvs, unsigned short* __restrict__ w1b,
    unsigned short* __restrict__ w2b, int* __restrict__ deg)
{
  if (blockIdx.x >= WCB) {  // ---- deg zero path ----
    int idx = ((blockIdx.x - WCB) * 256 + threadIdx.x) * 4;
    if (idx + 3 < N_NODES) *(int4*)(deg + idx) = (int4){0, 0, 0, 0};
    else {
      for (int t = 0; t < 4; t++)
        if (idx + t < N_NODES) deg[idx + t] = 0;
    }
    return;
  }
  int i = blockIdx.x * 256 + threadIdx.x;  // [0, 49152) float4 groups
  const float4* src;
  unsigned short* dst;
  if (i < 16384) {
    int part = i >> 12;
    src = ((part == 0) ? Wq : (part == 1) ? Wk : (part == 2) ? Wv : Ws) + (i & 4095);
    dst = wqkvs + i * 4;
  } else if (i < 32768) {
    src = W1 + (i - 16384); dst = w1b + (size_t)(i - 16384) * 4;
  } else {
    src = W2 + (i - 32768); dst = w2b + (size_t)(i - 32768) * 4;
  }
  float4 v = *src;
  ushort4 o;
  o.x = f2bf(v.x); o.y = f2bf(v.y); o.z = f2bf(v.z); o.w = f2bf(v.w);
  *(ushort4*)dst = o;
}

// ---- fused [LN1 + QKVS projection via bf16 MFMA | degree count] -------------
// 128-node tile, 512 threads (8 waves). Wave w: matrix w>>1, node-half w&1.
// The two waves sharing a matrix hit the same weight lines (L1 reuse) ->
// per-node L2 weight traffic halves vs the 64-node tile.
// kv layout: [node][32 chunks of 8B]; chunk c = {k[4c..4c+3] | v[4c..4c+3]}.
__global__ __launch_bounds__(512) void qkvs_kernel(
    const float* __restrict__ x,
    const float* __restrict__ g1, const float* __restrict__ bln,
    const unsigned short* __restrict__ wqkvs,
    const float* __restrict__ bq, const float* __restrict__ bk,
    const float* __restrict__ bv, const float* __restrict__ bs,
    unsigned short* __restrict__ qb, unsigned char* __restrict__ kvb,
    unsigned short* __restrict__ sb,
    const int* __restrict__ ei, int* __restrict__ deg, int n)
{
  if (blockIdx.x >= NQB2) {  // ---- degree count path ----
    for (int e = (blockIdx.x - NQB2) * 512 + threadIdx.x; e < E_EDGES;
         e += NQB2 * 512)
      atomicAdd(deg + ei[E_EDGES + e], 1);
    return;
  }
  __shared__ short lnA[128][128];
  int node0 = blockIdx.x * 128;
  int tid = threadIdx.x;
  int g = tid >> 4, gl = tid & 15, c0 = gl * 8;  // g in [0,32)
  {
    float gv[8], bv2[8];
    *(float4*)&gv[0] = *(const float4*)(g1 + c0);
    *(float4*)&gv[4] = *(const float4*)(g1 + c0 + 4);
    *(float4*)&bv2[0] = *(const float4*)(bln + c0);
    *(float4*)&bv2[4] = *(const float4*)(bln + c0 + 4);
    #pragma unroll
    for (int ni = 0; ni < 4; ni++) {
      int nl = ni * 32 + g;
      int node = node0 + nl;
      short8 h8 = {0, 0, 0, 0, 0, 0, 0, 0};
      if (node < n) {
        float vals[8];
        const float* row = x + (size_t)node * HID + c0;
        *(float4*)&vals[0] = *(const float4*)row;
        *(float4*)&vals[4] = *(const float4*)(row + 4);
        float sum = 0.f;
        #pragma unroll
        for (int j = 0; j < 8; j++) sum += vals[j];
        sum += __shfl_xor(sum, 8); sum += __shfl_xor(sum, 4);
        sum += __shfl_xor(sum, 2); sum += __shfl_xor(sum, 1);
        float mu = sum * (1.f / 128.f);
        float sq = 0.f;
        #pragma unroll
        for (int j = 0; j < 8; j++) { float d = vals[j] - mu; sq += d * d; }
        sq += __shfl_xor(sq, 8); sq += __shfl_xor(sq, 4);
        sq += __shfl_xor(sq, 2); sq += __shfl_xor(sq, 1);
        float rstd = rsqrtf(sq * (1.f / 128.f) + 1e-5f);
        #pragma unroll
        for (int j = 0; j < 8; j++)
          h8[j] = (short)f2bf((vals[j] - mu) * rstd * gv[j] + bv2[j]);
      }
      *(short8*)&lnA[nl][(gl ^ (nl & 7)) * 8] = h8;
    }
  }
  __syncthreads();
  int w = tid >> 6, lane = tid & 63;
  int m = w >> 1, h = w & 1;       // matrix, node-half
  int lg = lane >> 4, ll = lane & 15;
  int nbase = h * 64;              // node-tile base within LDS
  short8 bfr[4][4];
  #pragma unroll
  for (int nt = 0; nt < 4; nt++) {
    int arow = nbase + nt * 16 + ll;
    #pragma unroll
    for (int kt = 0; kt < 4; kt++)
      bfr[nt][kt] = *(const short8*)&lnA[arow][((kt * 4 + lg) ^ (ll & 7)) * 8];
  }
  const float* biasp = (m == 0) ? bq : (m == 1) ? bk : (m == 2) ? bv : bs;
  bool ok[4];
  #pragma unroll
  for (int nt = 0; nt < 4; nt++) ok[nt] = (node0 + nbase + nt * 16 + ll) < n;
  for (int ci = 0; ci < 8; ci++) {
    const unsigned short* wrow = wqkvs + (size_t)(m * 128 + ci * 16 + ll) * 128 + lg * 8;
    short8 af[4];
    #pragma unroll
    for (int kt = 0; kt < 4; kt++) af[kt] = *(const short8*)(wrow + kt * 32);
    f32x4 acc[4];
    #pragma unroll
    for (int nt = 0; nt < 4; nt++) acc[nt] = (f32x4){0.f, 0.f, 0.f, 0.f};
    #pragma unroll
    for (int kt = 0; kt < 4; kt++)
      #pragma unroll
      for (int nt = 0; nt < 4; nt++)
        acc[nt] = __builtin_amdgcn_mfma_f32_16x16x32_bf16(af[kt], bfr[nt][kt], acc[nt], 0, 0, 0);
    int jj = ci * 16 + lg * 4;  // 4 consecutive channels within this matrix
    float4 bq4 = *(const float4*)(biasp + jj);
    #pragma unroll
    for (int nt = 0; nt < 4; nt++) {
      if (!ok[nt]) continue;
      int node = node0 + nbase + nt * 16 + ll;
      float v0 = acc[nt][0] + bq4.x, v1 = acc[nt][1] + bq4.y;
      float v2 = acc[nt][2] + bq4.z, v3 = acc[nt][3] + bq4.w;
      if (m == 0 || m == 3) {
        ushort4 o;
        o.x = f2bf(v0); o.y = f2bf(v1); o.z = f2bf(v2); o.w = f2bf(v3);
        *(ushort4*)((m == 0 ? qb : sb) + (size_t)node * HID + jj) = o;
      } else {
        // chunk (jj>>2): k-word at +0, v-word at +4
        unsigned word = (unsigned)pk_fp8(v0, v1) | ((unsigned)pk_fp8(v2, v3) << 16);
        *(unsigned*)(kvb + (unsigned)node * 256 + (jj >> 2) * 8 + (m == 1 ? 0 : 4)) = word;
      }
    }
  }
}

// -------- CSR build: per-block degree sums (coalesced int4 reads) ------------
__global__ __launch_bounds__(256) void scan1_kernel(
    const int* __restrict__ deg, int* __restrict__ bsum)
{
  __shared__ int wsum[4];
  int b = blockIdx.x;
  int idx = b * SCAN_BLK + threadIdx.x * 4;
  int4 v = {0, 0, 0, 0};
  if (idx + 3 < N_NODES) v = *(const int4*)(deg + idx);
  else {
    if (idx     < N_NODES) v.x = deg[idx];
    if (idx + 1 < N_NODES) v.y = deg[idx + 1];
    if (idx + 2 < N_NODES) v.z = deg[idx + 2];
    if (idx + 3 < N_NODES) v.w = deg[idx + 3];
  }
  int s = v.x + v.y + v.z + v.w;
  for (int m = 1; m < 64; m <<= 1) s += __shfl_xor(s, m);
  int lane = threadIdx.x & 63, w = threadIdx.x >> 6;
  if (lane == 0) wsum[w] = s;
  __syncthreads();
  if (threadIdx.x == 0) bsum[b] = wsum[0] + wsum[1] + wsum[2] + wsum[3];
}

// -------- CSR build: block-local exclusive scan + global offset --------------
__global__ __launch_bounds__(256) void scan2_kernel(
    const int* __restrict__ deg, const int* __restrict__ bsum,
    int* __restrict__ row_start, int* __restrict__ cursor)
{
  __shared__ int boff_s;
  __shared__ int wsum[4];
  int b = blockIdx.x;
  int tid = threadIdx.x;
  int lane = tid & 63, w = tid >> 6;
  if (tid < 64) {  // block offset = sum of bsum[0..b)  (NSB=49 < 64)
    int v = (lane < b) ? bsum[lane] : 0;
    for (int m = 1; m < 64; m <<= 1) v += __shfl_xor(v, m);
    if (lane == 0) boff_s = v;
  }
  int idx = b * SCAN_BLK + tid * 4;
  int4 v = {0, 0, 0, 0};
  if (idx + 3 < N_NODES) v = *(const int4*)(deg + idx);
  else {
    if (idx     < N_NODES) v.x = deg[idx];
    if (idx + 1 < N_NODES) v.y = deg[idx + 1];
    if (idx + 2 < N_NODES) v.z = deg[idx + 2];
    if (idx + 3 < N_NODES) v.w = deg[idx + 3];
  }
  int ts = v.x + v.y + v.z + v.w;
  int incl = ts;
  for (int m = 1; m < 64; m <<= 1) {
    int t = __shfl_up(incl, m);
    if (lane >= m) incl += t;
  }
  if (lane == 63) wsum[w] = incl;
  __syncthreads();
  int woff = 0;
  for (int i = 0; i < w; i++) woff += wsum[i];
  int excl = boff_s + woff + incl - ts;
  int4 o;
  o.x = excl;
  o.y = excl + v.x;
  o.z = excl + v.x + v.y;
  o.w = excl + v.x + v.y + v.z;
  if (idx + 3 < N_NODES) {
    *(int4*)(row_start + idx) = o;
    *(int4*)(cursor + idx) = o;
  } else {
    if (idx     < N_NODES) { row_start[idx]     = o.x; cursor[idx]     = o.x; }
    if (idx + 1 < N_NODES) { row_start[idx + 1] = o.y; cursor[idx + 1] = o.y; }
    if (idx + 2 < N_NODES) { row_start[idx + 2] = o.z; cursor[idx + 2] = o.z; }
    if (idx + 3 < N_NODES) { row_start[idx + 3] = o.w; cursor[idx + 3] = o.w; }
  }
}

// -------- CSR build: scatter unified 16B records -----------------------------
// rec = {src_byteoff:int, attr01:2xbf16, attr23:2xbf16, pad}
__global__ __launch_bounds__(256) void scatter_kernel(
    const int* __restrict__ ei, const float4* __restrict__ attr,
    int* __restrict__ cursor, uint4* __restrict__ csr_rec)
{
  int e = blockIdx.x * 256 + threadIdx.x;
  if (e >= E_EDGES) return;
  int dst = ei[E_EDGES + e];
  float4 a4 = attr[e];
  int pos = atomicAdd(cursor + dst, 1);
  uint4 rec;
  rec.x = (unsigned)(ei[e] * 256);  // pre-multiplied byte offset into kvb
  rec.y = (unsigned)f2bf(a4.x) | ((unsigned)f2bf(a4.y) << 16);
  rec.z = (unsigned)f2bf(a4.z) | ((unsigned)f2bf(a4.w) << 16);
  rec.w = 0u;
  csr_rec[pos] = rec;
}

// -------- Gather + combine: 1 wave per dst node, 2 edge slots x 32 lanes -----
// q·(k+e) = q·k + (q^T We)·attr ;  Σ a_j e_j = We (Σ a_j attr_j).
// Lane = 4 channels (8B kv chunk); slot s = lane>>5 handles edge j+s.
// Unified 16B records scalarized via readfirstlane -> s_load_dwordx4; attr
// decoded from bf16 pairs; 2-deep SGPR record pipeline; kv on vector path.
__global__ __launch_bounds__(256) void gather_kernel(
    const int* __restrict__ row_start, const int* __restrict__ deg,
    const uint4* __restrict__ csr_rec,
    const float* __restrict__ We,
    const unsigned short* __restrict__ qb, const unsigned char* __restrict__ kvb,
    const float* __restrict__ x, const unsigned short* __restrict__ sb,
    const float* __restrict__ Wb, unsigned short* __restrict__ xnb, int n)
{
  int node = (blockIdx.x * blockDim.x + threadIdx.x) >> 6;
  if (node >= n) return;
  int nodeu = __builtin_amdgcn_readfirstlane(node);
  int lane = threadIdx.x & 63;
  int hl = lane & 31;   // half-lane: channel chunk
  int s  = lane >> 5;   // edge slot
  int c0 = hl * 4;      // 4 channels per lane
  const unsigned short* qrow = qb + (size_t)nodeu * HID;
  ushort4 q4 = *(const ushort4*)(qrow + c0);
  float q0 = bf2f(q4.x), q1 = bf2f(q4.y), q2 = bf2f(q4.z), q3 = bf2f(q4.w);
  float4 wr0 = *(const float4*)(We + (c0 + 0) * 4);
  float4 wr1 = *(const float4*)(We + (c0 + 1) * 4);
  float4 wr2 = *(const float4*)(We + (c0 + 2) * 4);
  float4 wr3 = *(const float4*)(We + (c0 + 3) * 4);
  float qwe0 = q0 * wr0.x + q1 * wr1.x + q2 * wr2.x + q3 * wr3.x;
  float qwe1 = q0 * wr0.y + q1 * wr1.y + q2 * wr2.y + q3 * wr3.y;
  float qwe2 = q0 * wr0.z + q1 * wr1.z + q2 * wr2.z + q3 * wr3.z;
  float qwe3 = q0 * wr0.w + q1 * wr1.w + q2 * wr2.w + q3 * wr3.w;
  qwe0 += __shfl_xor(qwe0, 1); qwe0 += __shfl_xor(qwe0, 2); qwe0 += __shfl_xor(qwe0, 4);
  qwe1 += __shfl_xor(qwe1, 1); qwe1 += __shfl_xor(qwe1, 2); qwe1 += __shfl_xor(qwe1, 4);
  qwe2 += __shfl_xor(qwe2, 1); qwe2 += __shfl_xor(qwe2, 2); qwe2 += __shfl_xor(qwe2, 4);
  qwe3 += __shfl_xor(qwe3, 1); qwe3 += __shfl_xor(qwe3, 2); qwe3 += __shfl_xor(qwe3, 4);
  const float s2 = 0.17677669529663687f * 1.4426950408889634f;  // /sqrt(32)*log2e
  float q0s = q0 * s2, q1s = q1 * s2, q2s = q2 * s2, q3s = q3 * s2;
  qwe0 *= s2; qwe1 *= s2; qwe2 *= s2; qwe3 *= s2;
  float acc0 = 0.f, acc1 = 0.f, acc2 = 0.f, acc3 = 0.f, den = 0.f;
  float aat0 = 0.f, aat1 = 0.f, aat2 = 0.f, aat3 = 0.f;
  int rs = row_start[nodeu];
  int cnt = deg[nodeu];
  int re = rs + cnt;
  unsigned off = (unsigned)hl * 8;
  // current records (slots rs, rs+1) in SGPRs
  int i0 = __builtin_amdgcn_readfirstlane(min(rs,     E_EDGES - 1));
  int i1 = __builtin_amdgcn_readfirstlane(min(rs + 1, E_EDGES - 1));
  uint4 rC0 = csr_rec[i0];
  uint4 rC1 = csr_rec[i1];
  unsigned srcsel = s ? rC1.x : rC0.x;
  uint2 kvc = *(const uint2*)(kvb + srcsel + off);
  float4 ac;
  ac.x = s ? bf_lo(rC1.y) : bf_lo(rC0.y);
  ac.y = s ? bf_hi(rC1.y) : bf_hi(rC0.y);
  ac.z = s ? bf_lo(rC1.z) : bf_lo(rC0.z);
  ac.w = s ? bf_hi(rC1.z) : bf_hi(rC0.z);
  // next records (slots rs+2, rs+3) in SGPRs
  int i2 = __builtin_amdgcn_readfirstlane(min(rs + 2, E_EDGES - 1));
  int i3 = __builtin_amdgcn_readfirstlane(min(rs + 3, E_EDGES - 1));
  uint4 rN0 = csr_rec[i2];
  uint4 rN1 = csr_rec[i3];
  for (int j = rs; j < re; j += 2) {
    // issue next kv load (address from SGPR-resident records)
    unsigned srcn = s ? rN1.x : rN0.x;
    uint2 kvn = *(const uint2*)(kvb + srcn + off);
    float4 an;
    an.x = s ? bf_lo(rN1.y) : bf_lo(rN0.y);
    an.y = s ? bf_hi(rN1.y) : bf_hi(rN0.y);
    an.z = s ? bf_lo(rN1.z) : bf_lo(rN0.z);
    an.w = s ? bf_hi(rN1.z) : bf_hi(rN0.z);
    // issue scalar loads for the pair after next
    int p0 = __builtin_amdgcn_readfirstlane(min(j + 4, E_EDGES - 1));
    int p1 = __builtin_amdgcn_readfirstlane(min(j + 5, E_EDGES - 1));
    uint4 rP0 = csr_rec[p0];
    uint4 rP1 = csr_rec[p1];
    // compute on current
    f32x2 k01 = __builtin_amdgcn_cvt_pk_f32_fp8((int)kvc.x, false);
    f32x2 k23 = __builtin_amdgcn_cvt_pk_f32_fp8((int)kvc.x, true);
    float dot = q0s * k01.x + q1s * k01.y + q2s * k23.x + q3s * k23.y;
    dot += __shfl_xor(dot, 1);
    dot += __shfl_xor(dot, 2);
    dot += __shfl_xor(dot, 4);
    float e = exp2f(dot + qwe0 * ac.x + qwe1 * ac.y + qwe2 * ac.z + qwe3 * ac.w);
    e = (j + s < re) ? e : 0.f;  // slot validity (max-free softmax)
    den += e;
    aat0 += e * ac.x; aat1 += e * ac.y;
    aat2 += e * ac.z; aat3 += e * ac.w;
    f32x2 v01 = __builtin_amdgcn_cvt_pk_f32_fp8((int)kvc.y, false);
    f32x2 v23 = __builtin_amdgcn_cvt_pk_f32_fp8((int)kvc.y, true);
    acc0 += e * v01.x; acc1 += e * v01.y;
    acc2 += e * v23.x; acc3 += e * v23.y;
    // rotate
    kvc = kvn; ac = an;
    rN0 = rP0; rN1 = rP1;
  }
  // ---- combine the 2 edge slots ----
  acc0 += __shfl_xor(acc0, 32); acc1 += __shfl_xor(acc1, 32);
  acc2 += __shfl_xor(acc2, 32); acc3 += __shfl_xor(acc3, 32);
  den  += __shfl_xor(den, 32);
  aat0 += __shfl_xor(aat0, 32); aat1 += __shfl_xor(aat1, 32);
  aat2 += __shfl_xor(aat2, 32); aat3 += __shfl_xor(aat3, 32);
  float inv = 1.0f / (den + 1e-16f);
  float o0 = (acc0 + wr0.x * aat0 + wr0.y * aat1 + wr0.z * aat2 + wr0.w * aat3) * inv;
  float o1 = (acc1 + wr1.x * aat0 + wr1.y * aat1 + wr1.z * aat2 + wr1.w * aat3) * inv;
  float o2 = (acc2 + wr2.x * aat0 + wr2.y * aat1 + wr2.z * aat2 + wr2.w * aat3) * inv;
  float o3 = (acc3 + wr3.x * aat0 + wr3.y * aat1 + wr3.z * aat2 + wr3.w * aat3) * inv;
  // ---- fused combine: beta gate + first residual ----
  ushort4 sp4 = *(const ushort4*)(sb + (size_t)nodeu * HID + c0);
  float sk0 = bf2f(sp4.x), sk1 = bf2f(sp4.y), sk2 = bf2f(sp4.z), sk3 = bf2f(sp4.w);
  float4 wbA = *(const float4*)(Wb + c0);
  float4 wbB = *(const float4*)(Wb + 128 + c0);
  float4 wbC = *(const float4*)(Wb + 256 + c0);
  float bpart = o0 * (wbA.x + wbC.x) + sk0 * (wbB.x - wbC.x) +
                o1 * (wbA.y + wbC.y) + sk1 * (wbB.y - wbC.y) +
                o2 * (wbA.z + wbC.z) + sk2 * (wbB.z - wbC.z) +
                o3 * (wbA.w + wbC.w) + sk3 * (wbB.w - wbC.w);
  bpart += __shfl_xor(bpart, 1); bpart += __shfl_xor(bpart, 2);
  bpart += __shfl_xor(bpart, 4); bpart += __shfl_xor(bpart, 8);
  bpart += __shfl_xor(bpart, 16);  // sum over 32 lanes (each half has full sum)
  float beta = 1.0f / (1.0f + exp2f(-bpart * 1.4426950408889634f));
  if (lane < 32) {
    float4 xv = *(const float4*)(x + (size_t)nodeu * HID + c0);
    ushort4 o4;
    o4.x = f2bf(xv.x + beta * sk0 + (1.0f - beta) * o0);
    o4.y = f2bf(xv.y + beta * sk1 + (1.0f - beta) * o1);
    o4.z = f2bf(xv.z + beta * sk2 + (1.0f - beta) * o2);
    o4.w = f2bf(xv.w + beta * sk3 + (1.0f - beta) * o3);
    *(ushort4*)(xnb + (size_t)nodeu * HID + c0) = o4;
  }
}

// ---- fused LN2 + MLP (GEMM1 relu GEMM2) via bf16 MFMA + residual ------------
// 64-node tile, 512 threads (8 waves), 80KB LDS -> 2 blocks/CU. Halves the
// per-block weight stream (W1+W2 read once per 64 nodes instead of per 32)
// and doubles MFMA per weight fragment (4 node-tiles per wave).
__global__ __launch_bounds__(512) void mlp_kernel(
    const unsigned short* __restrict__ xnb,
    const float* __restrict__ g2, const float* __restrict__ b2ln,
    const unsigned short* __restrict__ w1b, const float* __restrict__ b1,
    const unsigned short* __restrict__ w2b, const float* __restrict__ b2,
    float* __restrict__ out, int n)
{
  __shared__ short lnA[64][128];
  __shared__ short tS[64][512];
  short* tsf = &tS[0][0];
  int node0 = blockIdx.x * 64;
  int tid = threadIdx.x;
  int g = tid >> 4, gl = tid & 15, c0 = gl * 8;
  {
    // 512 threads: 32 rows x 16 threads per pass, 2 passes
    float gv[8], bv2[8];
    *(float4*)&gv[0] = *(const float4*)(g2 + c0);
    *(float4*)&gv[4] = *(const float4*)(g2 + c0 + 4);
    *(float4*)&bv2[0] = *(const float4*)(b2ln + c0);
    *(float4*)&bv2[4] = *(const float4*)(b2ln + c0 + 4);
    #pragma unroll
    for (int ni = 0; ni < 2; ni++) {
      int nl = ni * 32 + g;
      int node = node0 + nl;
      short8 h8 = {0, 0, 0, 0, 0, 0, 0, 0};
      if (node < n) {
        short8 raw = *(const short8*)(xnb + (size_t)node * HID + c0);
        float vals[8];
        #pragma unroll
        for (int j = 0; j < 8; j++) vals[j] = bf2f((unsigned short)raw[j]);
        float sum = 0.f;
        #pragma unroll
        for (int j = 0; j < 8; j++) sum += vals[j];
        sum += __shfl_xor(sum, 8); sum += __shfl_xor(sum, 4);
        sum += __shfl_xor(sum, 2); sum += __shfl_xor(sum, 1);
        float mu = sum * (1.f / 128.f);
        float sq = 0.f;
        #pragma unroll
        for (int j = 0; j < 8; j++) { float d = vals[j] - mu; sq += d * d; }
        sq += __shfl_xor(sq, 8); sq += __shfl_xor(sq, 4);
        sq += __shfl_xor(sq, 2); sq += __shfl_xor(sq, 1);
        float rstd = rsqrtf(sq * (1.f / 128.f) + 1e-5f);
        #pragma unroll
        for (int j = 0; j < 8; j++)
          h8[j] = (short)f2bf((vals[j] - mu) * rstd * gv[j] + bv2[j]);
      }
      *(short8*)&lnA[nl][(gl ^ (nl & 7)) * 8] = h8;
    }
  }
  __syncthreads();
  int w = tid >> 6, lane = tid & 63;
  int lg = lane >> 4, ll = lane & 15;
  int swz = (ll & 7) << 1;  // tS granule XOR (node = nt*16+ll -> node&7 = ll&7)
  bool ok[4];
  #pragma unroll
  for (int nt = 0; nt < 4; nt++) ok[nt] = (node0 + nt * 16 + ll) < n;
  // ---- GEMM1: D[j][node]; wave w owns j-tiles [w*4, w*4+4), 4 node-tiles ----
  {
    short8 bfr1[4][4];
    #pragma unroll
    for (int nt = 0; nt < 4; nt++) {
      int arow = nt * 16 + ll;
      #pragma unroll
      for (int kt = 0; kt < 4; kt++)
        bfr1[nt][kt] = *(const short8*)&lnA[arow][((kt * 4 + lg) ^ (ll & 7)) * 8];
    }
    for (int ji = 0; ji < 4; ji++) {
      int jt = w * 4 + ji;
      const unsigned short* wrow = w1b + (size_t)(jt * 16 + ll) * 128 + lg * 8;
      short8 af[4];
      #pragma unroll
      for (int kt = 0; kt < 4; kt++) af[kt] = *(const short8*)(wrow + kt * 32);
      f32x4 acc[4];
      #pragma unroll
      for (int nt = 0; nt < 4; nt++) acc[nt] = (f32x4){0.f, 0.f, 0.f, 0.f};
      #pragma unroll
      for (int kt = 0; kt < 4; kt++)
        #pragma unroll
        for (int nt = 0; nt < 4; nt++)
          acc[nt] = __builtin_amdgcn_mfma_f32_16x16x32_bf16(af[kt], bfr1[nt][kt], acc[nt], 0, 0, 0);
      float4 bj = *(const float4*)(b1 + jt * 16 + lg * 4);
      int gr = jt * 4 + lg;  // logical 8B granule (4 consecutive j)
      #pragma unroll
      for (int nt = 0; nt < 4; nt++) {
        int nl = nt * 16 + ll;
        ushort4 o;
        o.x = f2bf(fmaxf(acc[nt][0] + bj.x, 0.f));
        o.y = f2bf(fmaxf(acc[nt][1] + bj.y, 0.f));
        o.z = f2bf(fmaxf(acc[nt][2] + bj.z, 0.f));
        o.w = f2bf(fmaxf(acc[nt][3] + bj.w, 0.f));
        *(ushort4*)&tsf[nl * 512 + (gr ^ swz) * 4] = o;
      }
    }
  }
  __syncthreads();
  // ---- GEMM2: D[c][node]; wave w owns c-tile w, 4 node-tiles ---------------
  {
    int ct = w;
    f32x4 acc[4];
    #pragma unroll
    for (int nt = 0; nt < 4; nt++) acc[nt] = (f32x4){0.f, 0.f, 0.f, 0.f};
    const unsigned short* wrow = w2b + (size_t)(ct * 16 + ll) * 512 + lg * 8;
    #pragma unroll
    for (int kt = 0; kt < 16; kt++) {
      short8 af = *(const short8*)(wrow + kt * 32);
      int G = kt * 8 + lg * 2;  // logical granule pair base (even)
      #pragma unroll
      for (int nt = 0; nt < 4; nt++) {
        short8 bfrag = *(const short8*)&tsf[(nt * 16 + ll) * 512 + (G ^ swz) * 4];
        acc[nt] = __builtin_amdgcn_mfma_f32_16x16x32_bf16(af, bfrag, acc[nt], 0, 0, 0);
      }
    }
    int c = ct * 16 + lg * 4;
    float4 b2q = *(const float4*)(b2 + c);
    #pragma unroll
    for (int nt = 0; nt < 4; nt++) {
      if (!ok[nt]) continue;
      int node = node0 + nt * 16 + ll;
      ushort4 xr = *(const ushort4*)(xnb + (size_t)node * HID + c);
      float4 o;
      o.x = bf2f(xr.x) + acc[nt][0] + b2q.x;
      o.y = bf2f(xr.y) + acc[nt][1] + b2q.y;
      o.z = bf2f(xr.z) + acc[nt][2] + b2q.z;
      o.w = bf2f(xr.w) + acc[nt][3] + b2q.w;
      *(float4*)(out + (size_t)node * HID + c) = o;
    }
  }
}

extern "C" void kernel_launch(void* const* d_in, const int* in_sizes, int n_in,
                              void* d_out, int out_size, void* d_ws, size_t ws_size,
                              hipStream_t stream) {
  const float* x     = (const float*)d_in[0];
  const int*   ei    = (const int*)d_in[1];
  const float* attr  = (const float*)d_in[2];
  const float* ln1_g = (const float*)d_in[3];
  const float* ln1_b = (const float*)d_in[4];
  const float* Wq    = (const float*)d_in[5];
  const float* bq    = (const float*)d_in[6];
  const float* Wk    = (const float*)d_in[7];
  const float* bk    = (const float*)d_in[8];
  const float* Wv    = (const float*)d_in[9];
  const float* bv    = (const float*)d_in[10];
  const float* We    = (const float*)d_in[11];
  const float* Wskip = (const float*)d_in[12];
  const float* bskip = (const float*)d_in[13];
  const float* Wbeta = (const float*)d_in[14];
  const float* ln2_g = (const float*)d_in[15];
  const float* ln2_b = (const float*)d_in[16];
  const float* W1    = (const float*)d_in[17];
  const float* b1    = (const float*)d_in[18];
  const float* W2    = (const float*)d_in[19];
  const float* b2    = (const float*)d_in[20];
  float* out = (float*)d_out;
  float* ws  = (float*)d_ws;

  size_t NH  = (size_t)N_NODES * HID;  // 6.4M elements
  size_t NHf = NH / 2;                 // ushort array size in float units
  unsigned short* sb  = (unsigned short*)ws;             // [N][128] bf16 skip
  unsigned short* xnb = (unsigned short*)(ws + NHf);     // [N][128] bf16 xn
  unsigned short* qb  = (unsigned short*)(ws + 2 * NHf); // [N][128] bf16 q
  unsigned char*  kvb = (unsigned char*)(ws + 3 * NHf);  // [N][256] fp8 chunks
  float* base2 = ws + 3 * NHf + (size_t)N_NODES * 256 / 4;
  int* deg       = (int*)base2;
  int* row_start = deg + N_NODES;
  int* cursor    = row_start + N_NODES;
  // 3*N ints = 150000; pad to 16B boundary (150000 % 4 == 0) -> csr_rec aligned
  uint4* csr_rec = (uint4*)(base2 + 150000);
  unsigned short* wqkvs = (unsigned short*)(base2 + 150000 + (size_t)E_EDGES * 4);
  unsigned short* w1b   = wqkvs + 65536;
  unsigned short* w2b   = w1b + 65536;
  int* bsum = (int*)(w2b + 65536);  // NSB=49 block sums

  wcvt_kernel<<<WCB + NSB, 256, 0, stream>>>(
      (const float4*)Wq, (const float4*)Wk, (const float4*)Wv,
      (const float4*)Wskip, (const float4*)W1, (const float4*)W2,
      wqkvs, w1b, w2b, deg);
  qkvs_kernel<<<2 * NQB2, 512, 0, stream>>>(
      x, ln1_g, ln1_b, wqkvs, bq, bk, bv, bskip, qb, kvb, sb, ei, deg, N_NODES);
  scan1_kernel<<<NSB, 256, 0, stream>>>(deg, bsum);
  scan2_kernel<<<NSB, 256, 0, stream>>>(deg, bsum, row_start, cursor);
  scatter_kernel<<<(E_EDGES + 255) / 256, 256, 0, stream>>>(
      ei, (const float4*)attr, cursor, csr_rec);
  gather_kernel<<<(N_NODES * 64 + 255) / 256, 256, 0, stream>>>(
      row_start, deg, csr_rec, We, qb, kvb, x, sb, Wbeta, xnb, N_NODES);
  mlp_kernel<<<(N_NODES + 63) / 64, 512, 0, stream>>>(
      xnb, ln2_g, ln2_b, w1b, b1, w2b, b2, out, N_NODES);
}